// Round 1
// baseline (277.723 us; speedup 1.0000x reference)
//
#include <hip/hip_runtime.h>
#include <cstdint>
#include <cstddef>

typedef __bf16 bf16;
typedef __attribute__((ext_vector_type(8))) __bf16 bf16x8;
typedef __attribute__((ext_vector_type(4))) float f32x4;

#define T_N   2048
#define HID_N 2048
#define NH    16
#define NKV   8
#define HD    128

#define MFMA(a, b, c) __builtin_amdgcn_mfma_f32_16x16x32_bf16((a), (b), (c), 0, 0, 0)

__device__ __forceinline__ void gl_lds16(const void* g, void* l) {
    __builtin_amdgcn_global_load_lds(
        (const __attribute__((address_space(1))) unsigned int*)g,
        (__attribute__((address_space(3))) unsigned int*)l,
        16, 0, 0);
}

// ---------------- fp32 -> bf16 convert (weights) ----------------
__global__ __launch_bounds__(256) void k_f2b(const float* __restrict__ in,
                                             bf16* __restrict__ out, int n) {
    int i = (blockIdx.x * 256 + threadIdx.x) * 8;
    if (i >= n) return;
    const float4* p = (const float4*)(in + i);
    float4 a = p[0], b = p[1];
    bf16x8 v;
    v[0] = (bf16)a.x; v[1] = (bf16)a.y; v[2] = (bf16)a.z; v[3] = (bf16)a.w;
    v[4] = (bf16)b.x; v[5] = (bf16)b.y; v[6] = (bf16)b.z; v[7] = (bf16)b.w;
    *(bf16x8*)(out + i) = v;
}

// ---------------- hidden RMSNorm -> bf16 ----------------
__global__ __launch_bounds__(256) void k_rmsnorm(const float* __restrict__ x,
                                                 const float* __restrict__ w,
                                                 bf16* __restrict__ out) {
    int row = blockIdx.x, tid = threadIdx.x;
    const float* xr = x + (size_t)row * HID_N;
    float4 a = ((const float4*)xr)[tid * 2];
    float4 b = ((const float4*)xr)[tid * 2 + 1];
    float ss = a.x*a.x + a.y*a.y + a.z*a.z + a.w*a.w
             + b.x*b.x + b.y*b.y + b.z*b.z + b.w*b.w;
    #pragma unroll
    for (int m = 32; m; m >>= 1) ss += __shfl_xor(ss, m);
    __shared__ float red[4];
    if ((tid & 63) == 0) red[tid >> 6] = ss;
    __syncthreads();
    float tot = red[0] + red[1] + red[2] + red[3];
    float rs = rsqrtf(tot * (1.0f / HID_N) + 1e-6f);
    const float4* wr = (const float4*)(w + tid * 8);
    float4 wa = wr[0], wb = wr[1];
    bf16x8 v;
    v[0] = (bf16)(a.x * rs * wa.x); v[1] = (bf16)(a.y * rs * wa.y);
    v[2] = (bf16)(a.z * rs * wa.z); v[3] = (bf16)(a.w * rs * wa.w);
    v[4] = (bf16)(b.x * rs * wb.x); v[5] = (bf16)(b.y * rs * wb.y);
    v[6] = (bf16)(b.z * rs * wb.z); v[7] = (bf16)(b.w * rs * wb.w);
    *(bf16x8*)(out + (size_t)row * HID_N + tid * 8) = v;
}

// ---------------- GEMM: C[M][N] = A[M][K] * B[N][K]^T (bf16 in, fp32 out) ----
// 128x128 tile, BK=64, 256 threads (4 waves, 2x2), global_load_lds staging
// with XOR-swizzled source so ds_read_b128 fragment reads are ~conflict-free.
__global__ __launch_bounds__(256, 2) void k_gemm_bt(const bf16* __restrict__ A,
                                                    const bf16* __restrict__ B,
                                                    float* __restrict__ C,
                                                    int M, int N, int K) {
    __shared__ __attribute__((aligned(16))) bf16 As[128 * 64];
    __shared__ __attribute__((aligned(16))) bf16 Bs[128 * 64];
    const int tid = threadIdx.x;
    const int lane = tid & 63, wid = tid >> 6;
    const int wm = wid >> 1, wn = wid & 1;
    const int r = lane & 15, g = lane >> 4;
    const size_t bm = (size_t)blockIdx.y * 128, bn = (size_t)blockIdx.x * 128;

    f32x4 acc[4][4] = {};

    const int srow = tid >> 3;   // 0..31 (+32c)
    const int schk = tid & 7;    // 16B chunk position within a row

    for (int k0 = 0; k0 < K; k0 += 64) {
        __syncthreads();
        #pragma unroll
        for (int c = 0; c < 4; c++) {
            int row = c * 32 + srow;
            int ka = (schk ^ (row & 7)) << 3;   // swizzled k element offset
            gl_lds16(A + (bm + row) * (size_t)K + k0 + ka,
                     (char*)As + c * 4096 + tid * 16);
            gl_lds16(B + (bn + row) * (size_t)K + k0 + ka,
                     (char*)Bs + c * 4096 + tid * 16);
        }
        __syncthreads();
        #pragma unroll
        for (int kk = 0; kk < 2; kk++) {
            bf16x8 af[4], bfr[4];
            #pragma unroll
            for (int m = 0; m < 4; m++) {
                int row = wm * 64 + m * 16 + r;
                af[m] = *(const bf16x8*)(As + row * 64 + (((kk * 4 + g) ^ (row & 7)) << 3));
            }
            #pragma unroll
            for (int n = 0; n < 4; n++) {
                int row = wn * 64 + n * 16 + r;
                bfr[n] = *(const bf16x8*)(Bs + row * 64 + (((kk * 4 + g) ^ (row & 7)) << 3));
            }
            #pragma unroll
            for (int m = 0; m < 4; m++)
                #pragma unroll
                for (int n = 0; n < 4; n++)
                    acc[m][n] = MFMA(af[m], bfr[n], acc[m][n]);
        }
    }
    #pragma unroll
    for (int m = 0; m < 4; m++)
        #pragma unroll
        for (int n = 0; n < 4; n++)
            #pragma unroll
            for (int j = 0; j < 4; j++) {
                size_t row = bm + wm * 64 + m * 16 + g * 4 + j;
                size_t col = bn + wn * 64 + n * 16 + r;
                C[row * (size_t)N + col] = acc[m][n][j];
            }
}

// ---------------- per-head RMSNorm + RoPE (q,k), bf16 cast (v) ----------------
// grid (T, 32): y<16 -> q head, 16..23 -> k head, 24..31 -> v head. 128 threads.
__global__ __launch_bounds__(128) void k_normrope(const float* __restrict__ qkv,
                                                  const float* __restrict__ qw,
                                                  const float* __restrict__ kw,
                                                  const int* __restrict__ pos,
                                                  bf16* __restrict__ q,
                                                  bf16* __restrict__ k,
                                                  bf16* __restrict__ v) {
    int t = blockIdx.x, hs = blockIdx.y, d = threadIdx.x;
    const float* base = qkv + (size_t)t * 4096;
    if (hs >= 24) {
        int hv = hs - 24;
        v[((size_t)t * NKV + hv) * HD + d] = (bf16)base[3072 + hv * 128 + d];
        return;
    }
    bool isq = hs < 16;
    int h = isq ? hs : hs - 16;
    float x = isq ? base[h * 128 + d] : base[2048 + h * 128 + d];
    float ss = x * x;
    #pragma unroll
    for (int m = 32; m; m >>= 1) ss += __shfl_xor(ss, m);
    __shared__ float red[2];
    if ((d & 63) == 0) red[d >> 6] = ss;
    __syncthreads();
    float rs = rsqrtf((red[0] + red[1]) * (1.0f / HD) + 1e-6f);
    float nx = x * rs * (isq ? qw[d] : kw[d]);
    __shared__ float sh[128];
    sh[d] = nx;
    __syncthreads();
    float other = sh[d ^ 64];
    int j = d & 63;
    float ang = (float)pos[t] * __powf(10000.f, -(float)j * (1.f / 64.f));
    float s, c;
    __sincosf(ang, &s, &c);
    float o = (d < 64) ? (nx * c - other * s) : (nx * c + other * s);
    bf16* dst = isq ? (q + ((size_t)t * NH + h) * HD + d)
                    : (k + ((size_t)t * NKV + h) * HD + d);
    *dst = (bf16)o;
}

// ---------------- flash attention (causal, GQA 2:1) ----------------
// grid (H=16, 32 q-tiles zig-zagged), 256 threads = 4 waves, wave = 16 q rows.
__global__ __launch_bounds__(256, 2) void k_flash(const bf16* __restrict__ Q,
                                                  const bf16* __restrict__ K,
                                                  const bf16* __restrict__ V,
                                                  bf16* __restrict__ O) {
    __shared__ __attribute__((aligned(16))) bf16 Ks[32][128];
    __shared__ __attribute__((aligned(16))) bf16 Vt[128][48];
    __shared__ float Pl[4][16][36];
    const int tid = threadIdx.x, lane = tid & 63, w = tid >> 6;
    const int r = lane & 15, grp = lane >> 4;
    const int h = blockIdx.x;
    const int by = blockIdx.y;
    const int qt = (by < 16) ? (2 * by) : (63 - 2 * by);  // zig-zag load balance
    const int q0 = qt * 64;
    const int g = h >> 1;  // kv head

    const int qrow = q0 + w * 16 + r;
    bf16x8 qf[4];
    #pragma unroll
    for (int ks = 0; ks < 4; ks++)
        qf[ks] = *(const bf16x8*)(Q + ((size_t)qrow * NH + h) * HD + ks * 32 + grp * 8);

    f32x4 o_acc[8] = {};
    float m_run[4] = {-1e30f, -1e30f, -1e30f, -1e30f};
    float l_run[4] = {0.f, 0.f, 0.f, 0.f};
    const int myqmax = q0 + w * 16 + 15;

    for (int kv0 = 0; kv0 < q0 + 64; kv0 += 32) {
        __syncthreads();
        {
            int rowk = tid >> 4;     // 0..15
            int posc = tid & 15;     // 16B chunk pos within 256B row
            #pragma unroll
            for (int c = 0; c < 2; c++) {
                int row = c * 16 + rowk;
                int dofs = (posc ^ (row & 15)) << 3;  // swizzled d offset
                gl_lds16(K + ((size_t)(kv0 + row) * NKV + g) * HD + dofs,
                         (char*)Ks + c * 4096 + tid * 16);
            }
            #pragma unroll
            for (int c = 0; c < 2; c++) {
                int row = c * 16 + rowk;
                int dofs = posc * 8;
                bf16x8 raw = *(const bf16x8*)(V + ((size_t)(kv0 + row) * NKV + g) * HD + dofs);
                #pragma unroll
                for (int i = 0; i < 8; i++) Vt[dofs + i][row] = raw[i];
            }
        }
        __syncthreads();
        if (kv0 <= myqmax) {
            f32x4 S0 = {}, S1 = {};
            #pragma unroll
            for (int ks = 0; ks < 4; ks++) {
                int row0 = r;
                bf16x8 kf0 = *(const bf16x8*)(&Ks[row0][((ks * 4 + grp) ^ (row0 & 15)) << 3]);
                S0 = MFMA(qf[ks], kf0, S0);
                int row1 = 16 + r;
                bf16x8 kf1 = *(const bf16x8*)(&Ks[row1][((ks * 4 + grp) ^ (row1 & 15)) << 3]);
                S1 = MFMA(qf[ks], kf1, S1);
            }
            const float scale = 0.08838834764831845f;  // 128^-0.5
            float s0[4], s1[4];
            #pragma unroll
            for (int j = 0; j < 4; j++) {
                int qr = q0 + w * 16 + grp * 4 + j;
                s0[j] = ((kv0 + r) <= qr) ? S0[j] * scale : -1e30f;
                s1[j] = ((kv0 + 16 + r) <= qr) ? S1[j] * scale : -1e30f;
            }
            float alpha[4], p0[4], p1[4];
            #pragma unroll
            for (int j = 0; j < 4; j++) {
                float vv = fmaxf(s0[j], s1[j]);
                vv = fmaxf(vv, __shfl_xor(vv, 1));
                vv = fmaxf(vv, __shfl_xor(vv, 2));
                vv = fmaxf(vv, __shfl_xor(vv, 4));
                vv = fmaxf(vv, __shfl_xor(vv, 8));
                float mn = fmaxf(m_run[j], vv);
                alpha[j] = __expf(m_run[j] - mn);
                m_run[j] = mn;
                p0[j] = __expf(s0[j] - mn);
                p1[j] = __expf(s1[j] - mn);
                float rsm = p0[j] + p1[j];
                rsm += __shfl_xor(rsm, 1);
                rsm += __shfl_xor(rsm, 2);
                rsm += __shfl_xor(rsm, 4);
                rsm += __shfl_xor(rsm, 8);
                l_run[j] = l_run[j] * alpha[j] + rsm;
            }
            #pragma unroll
            for (int f = 0; f < 8; f++)
                #pragma unroll
                for (int j = 0; j < 4; j++) o_acc[f][j] *= alpha[j];
            #pragma unroll
            for (int j = 0; j < 4; j++) {
                Pl[w][grp * 4 + j][r] = p0[j];
                Pl[w][grp * 4 + j][16 + r] = p1[j];
            }
            bf16x8 pa;
            #pragma unroll
            for (int i = 0; i < 8; i++) pa[i] = (bf16)Pl[w][r][grp * 8 + i];
            #pragma unroll
            for (int f = 0; f < 8; f++) {
                bf16x8 vf = *(const bf16x8*)(&Vt[f * 16 + r][grp * 8]);
                o_acc[f] = MFMA(pa, vf, o_acc[f]);
            }
        }
    }
    #pragma unroll
    for (int f = 0; f < 8; f++)
        #pragma unroll
        for (int j = 0; j < 4; j++) {
            int qq = q0 + w * 16 + grp * 4 + j;
            int d = f * 16 + r;
            O[((size_t)qq * NH + h) * HD + d] = (bf16)(o_acc[f][j] / l_run[j]);
        }
}

// ---------------- launch ----------------
extern "C" void kernel_launch(void* const* d_in, const int* in_sizes, int n_in,
                              void* d_out, int out_size, void* d_ws, size_t ws_size,
                              hipStream_t stream) {
    const int*   pos  = (const int*)d_in[0];
    const float* hid  = (const float*)d_in[1];
    const float* lw   = (const float*)d_in[2];
    const float* qkvw = (const float*)d_in[3];
    const float* qnw  = (const float*)d_in[4];
    const float* knw  = (const float*)d_in[5];
    const float* ow   = (const float*)d_in[6];
    float* out = (float*)d_out;

    char* ws = (char*)d_ws;
    bf16*  qkvw_b = (bf16*)(ws);                          // 16 MB
    bf16*  ow_b   = (bf16*)(ws + (16u << 20));            // 8 MB
    bf16*  normed = (bf16*)(ws + (24u << 20));            // 8 MB
    float* qkvf   = (float*)(ws + (32u << 20));           // 32 MB
    bf16*  qb     = (bf16*)(ws + (64u << 20));            // 8 MB
    bf16*  kb     = (bf16*)(ws + (72u << 20));            // 4 MB
    bf16*  vb     = (bf16*)(ws + (76u << 20));            // 4 MB -> 80 MB total
    bf16*  ao     = normed;  // reuse: normed is dead after QKV GEMM

    k_f2b<<<4096, 256, 0, stream>>>(qkvw, qkvw_b, 4096 * 2048);
    k_f2b<<<2048, 256, 0, stream>>>(ow, ow_b, 2048 * 2048);
    k_rmsnorm<<<T_N, 256, 0, stream>>>(hid, lw, normed);
    k_gemm_bt<<<dim3(32, 16), 256, 0, stream>>>(normed, qkvw_b, qkvf, 2048, 4096, 2048);
    k_normrope<<<dim3(T_N, 32), 128, 0, stream>>>(qkvf, qnw, knw, pos, qb, kb, vb);
    k_flash<<<dim3(NH, 32), 256, 0, stream>>>(qb, kb, vb, ao);
    k_gemm_bt<<<dim3(16, 16), 256, 0, stream>>>(ao, ow_b, out, 2048, 2048, 2048);
}

// Round 2
// 205.588 us; speedup vs baseline: 1.3509x; 1.3509x over previous
//
#include <hip/hip_runtime.h>
#include <cstdint>
#include <cstddef>

typedef __bf16 bf16;
typedef __attribute__((ext_vector_type(8))) __bf16 bf16x8;
typedef __attribute__((ext_vector_type(4))) float f32x4;

#define T_N   2048
#define HID_N 2048
#define NH    16
#define NKV   8
#define HD    128

#define MFMA(a, b, c) __builtin_amdgcn_mfma_f32_16x16x32_bf16((a), (b), (c), 0, 0, 0)

__device__ __forceinline__ void gl_lds16(const void* g, void* l) {
    __builtin_amdgcn_global_load_lds(
        (const __attribute__((address_space(1))) unsigned int*)g,
        (__attribute__((address_space(3))) unsigned int*)l,
        16, 0, 0);
}

__device__ __forceinline__ uint32_t pk2(float a, float b) {
    union { bf16 h; unsigned short u; } ca, cb;
    ca.h = (bf16)a; cb.h = (bf16)b;
    return ((uint32_t)cb.u << 16) | ca.u;
}

// ---------------- fp32 -> bf16 convert (weights) ----------------
__global__ __launch_bounds__(256) void k_f2b(const float* __restrict__ in,
                                             bf16* __restrict__ out, int n) {
    int i = (blockIdx.x * 256 + threadIdx.x) * 8;
    if (i >= n) return;
    const float4* p = (const float4*)(in + i);
    float4 a = p[0], b = p[1];
    bf16x8 v;
    v[0] = (bf16)a.x; v[1] = (bf16)a.y; v[2] = (bf16)a.z; v[3] = (bf16)a.w;
    v[4] = (bf16)b.x; v[5] = (bf16)b.y; v[6] = (bf16)b.z; v[7] = (bf16)b.w;
    *(bf16x8*)(out + i) = v;
}

// ---------------- hidden RMSNorm -> bf16 ----------------
__global__ __launch_bounds__(256) void k_rmsnorm(const float* __restrict__ x,
                                                 const float* __restrict__ w,
                                                 bf16* __restrict__ out) {
    int row = blockIdx.x, tid = threadIdx.x;
    const float* xr = x + (size_t)row * HID_N;
    float4 a = ((const float4*)xr)[tid * 2];
    float4 b = ((const float4*)xr)[tid * 2 + 1];
    float ss = a.x*a.x + a.y*a.y + a.z*a.z + a.w*a.w
             + b.x*b.x + b.y*b.y + b.z*b.z + b.w*b.w;
    #pragma unroll
    for (int m = 32; m; m >>= 1) ss += __shfl_xor(ss, m);
    __shared__ float red[4];
    if ((tid & 63) == 0) red[tid >> 6] = ss;
    __syncthreads();
    float tot = red[0] + red[1] + red[2] + red[3];
    float rs = rsqrtf(tot * (1.0f / HID_N) + 1e-6f);
    const float4* wr = (const float4*)(w + tid * 8);
    float4 wa = wr[0], wb = wr[1];
    bf16x8 v;
    v[0] = (bf16)(a.x * rs * wa.x); v[1] = (bf16)(a.y * rs * wa.y);
    v[2] = (bf16)(a.z * rs * wa.z); v[3] = (bf16)(a.w * rs * wa.w);
    v[4] = (bf16)(b.x * rs * wb.x); v[5] = (bf16)(b.y * rs * wb.y);
    v[6] = (bf16)(b.z * rs * wb.z); v[7] = (bf16)(b.w * rs * wb.w);
    *(bf16x8*)(out + (size_t)row * HID_N + tid * 8) = v;
}

// ---------------- GEMM: C[M][N] = A[M][K] * B[N][K]^T (bf16 in, fp32 out) ----
__global__ __launch_bounds__(256, 2) void k_gemm_bt(const bf16* __restrict__ A,
                                                    const bf16* __restrict__ B,
                                                    float* __restrict__ C,
                                                    int M, int N, int K) {
    __shared__ __attribute__((aligned(16))) bf16 As[128 * 64];
    __shared__ __attribute__((aligned(16))) bf16 Bs[128 * 64];
    const int tid = threadIdx.x;
    const int lane = tid & 63, wid = tid >> 6;
    const int wm = wid >> 1, wn = wid & 1;
    const int r = lane & 15, g = lane >> 4;
    const size_t bm = (size_t)blockIdx.y * 128, bn = (size_t)blockIdx.x * 128;

    f32x4 acc[4][4] = {};

    const int srow = tid >> 3;   // 0..31
    const int schk = tid & 7;    // 16B chunk position within a row

    for (int k0 = 0; k0 < K; k0 += 64) {
        __syncthreads();
        #pragma unroll
        for (int c = 0; c < 4; c++) {
            int row = c * 32 + srow;
            int ka = (schk ^ (row & 7)) << 3;   // swizzled k element offset
            gl_lds16(A + (bm + row) * (size_t)K + k0 + ka,
                     (char*)As + c * 4096 + tid * 16);
            gl_lds16(B + (bn + row) * (size_t)K + k0 + ka,
                     (char*)Bs + c * 4096 + tid * 16);
        }
        __syncthreads();
        #pragma unroll
        for (int kk = 0; kk < 2; kk++) {
            bf16x8 af[4], bfr[4];
            #pragma unroll
            for (int m = 0; m < 4; m++) {
                int row = wm * 64 + m * 16 + r;
                af[m] = *(const bf16x8*)(As + row * 64 + (((kk * 4 + g) ^ (row & 7)) << 3));
            }
            #pragma unroll
            for (int n = 0; n < 4; n++) {
                int row = wn * 64 + n * 16 + r;
                bfr[n] = *(const bf16x8*)(Bs + row * 64 + (((kk * 4 + g) ^ (row & 7)) << 3));
            }
            #pragma unroll
            for (int m = 0; m < 4; m++)
                #pragma unroll
                for (int n = 0; n < 4; n++)
                    acc[m][n] = MFMA(af[m], bfr[n], acc[m][n]);
        }
    }
    #pragma unroll
    for (int m = 0; m < 4; m++)
        #pragma unroll
        for (int n = 0; n < 4; n++)
            #pragma unroll
            for (int j = 0; j < 4; j++) {
                size_t row = bm + wm * 64 + m * 16 + g * 4 + j;
                size_t col = bn + wn * 64 + n * 16 + r;
                C[row * (size_t)N + col] = acc[m][n][j];
            }
}

// ---------------- per-head RMSNorm + RoPE (q,k), bf16 cast (v) ----------------
__global__ __launch_bounds__(128) void k_normrope(const float* __restrict__ qkv,
                                                  const float* __restrict__ qw,
                                                  const float* __restrict__ kw,
                                                  const int* __restrict__ pos,
                                                  bf16* __restrict__ q,
                                                  bf16* __restrict__ k,
                                                  bf16* __restrict__ v) {
    int t = blockIdx.x, hs = blockIdx.y, d = threadIdx.x;
    const float* base = qkv + (size_t)t * 4096;
    if (hs >= 24) {
        int hv = hs - 24;
        v[((size_t)t * NKV + hv) * HD + d] = (bf16)base[3072 + hv * 128 + d];
        return;
    }
    bool isq = hs < 16;
    int h = isq ? hs : hs - 16;
    float x = isq ? base[h * 128 + d] : base[2048 + h * 128 + d];
    float ss = x * x;
    #pragma unroll
    for (int m = 32; m; m >>= 1) ss += __shfl_xor(ss, m);
    __shared__ float red[2];
    if ((d & 63) == 0) red[d >> 6] = ss;
    __syncthreads();
    float rs = rsqrtf((red[0] + red[1]) * (1.0f / HD) + 1e-6f);
    float nx = x * rs * (isq ? qw[d] : kw[d]);
    __shared__ float sh[128];
    sh[d] = nx;
    __syncthreads();
    float other = sh[d ^ 64];
    int j = d & 63;
    float ang = (float)pos[t] * __powf(10000.f, -(float)j * (1.f / 64.f));
    float s, c;
    __sincosf(ang, &s, &c);
    float o = (d < 64) ? (nx * c - other * s) : (nx * c + other * s);
    bf16* dst = isq ? (q + ((size_t)t * NH + h) * HD + d)
                    : (k + ((size_t)t * NKV + h) * HD + d);
    *dst = (bf16)o;
}

// ---------------- flash attention (causal, GQA 2:1), swapped-QK^T ----------------
// grid (H=16, 32 q-tiles zig-zagged), 256 threads = 4 waves, wave = 16 q rows.
// KVBLK=64. S^T = mfma(K,Q) so q is lane-local (q=r): softmax = 2 shfl_xor.
// P->A-frag redistribution via 16 ds_bpermute (no LDS round-trip).
// V staged transposed as Vt[d][k] via per-column ds_write_b128 (XOR k-chunk swizzle).
__global__ __launch_bounds__(256, 2) void k_flash(const bf16* __restrict__ Q,
                                                  const bf16* __restrict__ K,
                                                  const bf16* __restrict__ V,
                                                  bf16* __restrict__ O) {
    __shared__ __attribute__((aligned(16))) bf16 Ks[64 * 128];
    __shared__ __attribute__((aligned(16))) bf16 Vt[128 * 64];
    const int tid = threadIdx.x, lane = tid & 63, w = tid >> 6;
    const int r = lane & 15, g = lane >> 4;
    const int h = blockIdx.x, by = blockIdx.y;
    const int qt = (by < 16) ? (2 * by) : (63 - 2 * by);  // zig-zag pair balance
    const int q0 = qt * 64;
    const int gh = h >> 1;          // kv head
    const int q0w = q0 + w * 16;    // wave's first q row

    // Q fragment (B-operand): lane(r,g) holds Q[q0w+r][32ks+8g ..]
    bf16x8 qf[4];
    #pragma unroll
    for (int ks = 0; ks < 4; ks++)
        qf[ks] = *(const bf16x8*)(Q + ((size_t)(q0w + r) * NH + h) * HD + ks * 32 + g * 8);

    f32x4 o_acc[8] = {};
    float m_run = -1e30f, l_run = 0.f;

    const int rowk = tid >> 4, posc = tid & 15;  // K staging
    const int vd = tid & 127, vhalf = tid >> 7;  // V staging

    const float scale = 0.08838834764831845f;  // 128^-0.5

    for (int kv0 = 0; kv0 < q0 + 64; kv0 += 64) {
        __syncthreads();
        // ---- stage K rows [kv0, kv0+64), row-major, chunk^(row&7) swizzle ----
        #pragma unroll
        for (int c = 0; c < 4; c++) {
            int row = c * 16 + rowk;
            int srcc = posc ^ (row & 7);
            gl_lds16(K + ((size_t)(kv0 + row) * NKV + gh) * HD + srcc * 8,
                     (char*)Ks + c * 4096 + tid * 16);
        }
        // ---- stage V^T: thread owns column d=vd, k-chunks kb; one b128 write each ----
        #pragma unroll
        for (int it = 0; it < 4; it++) {
            int kb = vhalf + it * 2;
            const bf16* src = V + ((size_t)(kv0 + kb * 8) * NKV + gh) * HD + vd;
            bf16x8 col;
            #pragma unroll
            for (int i = 0; i < 8; i++) col[i] = src[(size_t)i * (NKV * HD)];
            *(bf16x8*)(Vt + vd * 64 + ((kb ^ (vd & 7)) * 8)) = col;
        }
        __syncthreads();

        if (kv0 <= q0w + 15) {
            // ---- S^T tiles: lane(r,g) gets S[q=r][k=16t+4g+j] ----
            float s[4][4];
            #pragma unroll
            for (int t = 0; t < 4; t++) {
                f32x4 S = {};
                #pragma unroll
                for (int ks = 0; ks < 4; ks++) {
                    int row = t * 16 + r;
                    bf16x8 kf = *(const bf16x8*)(Ks + row * 128 + (((4 * ks + g) ^ (row & 7)) * 8));
                    S = MFMA(kf, qf[ks], S);
                }
                #pragma unroll
                for (int j = 0; j < 4; j++) {
                    int kg = kv0 + t * 16 + 4 * g + j;
                    s[t][j] = (kg <= q0w + r) ? S[j] * scale : -1e30f;
                }
            }
            // ---- online softmax, q=r lane-local ----
            float mx = s[0][0];
            #pragma unroll
            for (int t = 0; t < 4; t++)
                #pragma unroll
                for (int j = 0; j < 4; j++) mx = fmaxf(mx, s[t][j]);
            mx = fmaxf(mx, __shfl_xor(mx, 16));
            mx = fmaxf(mx, __shfl_xor(mx, 32));
            float mn = fmaxf(m_run, mx);
            float alpha = __expf(m_run - mn);
            m_run = mn;
            float rs = 0.f;
            #pragma unroll
            for (int t = 0; t < 4; t++)
                #pragma unroll
                for (int j = 0; j < 4; j++) {
                    s[t][j] = __expf(s[t][j] - mn);
                    rs += s[t][j];
                }
            rs += __shfl_xor(rs, 16);
            rs += __shfl_xor(rs, 32);
            l_run = l_run * alpha + rs;

            // ---- rescale O by alpha of output row q=4g+j ----
            float aO[4];
            #pragma unroll
            for (int j = 0; j < 4; j++) aO[j] = __shfl(alpha, 4 * g + j);
            #pragma unroll
            for (int f = 0; f < 8; f++)
                #pragma unroll
                for (int j = 0; j < 4; j++) o_acc[f][j] *= aO[j];

            // ---- pack P to bf16 pairs, redistribute to A-frag via bpermute ----
            uint32_t w0[4], w1[4];
            #pragma unroll
            for (int t = 0; t < 4; t++) {
                w0[t] = pk2(s[t][0], s[t][1]);
                w1[t] = pk2(s[t][2], s[t][3]);
            }
            const int idx0 = (32 * (g & 1) + r) << 2;  // byte index of src lane
            const int idx1 = idx0 + 64;                // +16 lanes
            const bool hi = (g >> 1) != 0;
            bf16x8 pa[2];
            #pragma unroll
            for (int kk = 0; kk < 2; kk++) {
                int t0 = 2 * kk, t1 = 2 * kk + 1;
                uint32_t a0 = (uint32_t)__builtin_amdgcn_ds_bpermute(idx0, (int)w0[t0]);
                uint32_t b0 = (uint32_t)__builtin_amdgcn_ds_bpermute(idx0, (int)w0[t1]);
                uint32_t a1 = (uint32_t)__builtin_amdgcn_ds_bpermute(idx0, (int)w1[t0]);
                uint32_t b1 = (uint32_t)__builtin_amdgcn_ds_bpermute(idx0, (int)w1[t1]);
                uint32_t a2 = (uint32_t)__builtin_amdgcn_ds_bpermute(idx1, (int)w0[t0]);
                uint32_t b2 = (uint32_t)__builtin_amdgcn_ds_bpermute(idx1, (int)w0[t1]);
                uint32_t a3 = (uint32_t)__builtin_amdgcn_ds_bpermute(idx1, (int)w1[t0]);
                uint32_t b3 = (uint32_t)__builtin_amdgcn_ds_bpermute(idx1, (int)w1[t1]);
                union { uint32_t u[4]; bf16x8 v; } P;
                P.u[0] = hi ? b0 : a0;
                P.u[1] = hi ? b1 : a1;
                P.u[2] = hi ? b2 : a2;
                P.u[3] = hi ? b3 : a3;
                pa[kk] = P.v;
            }

            // ---- PV: O[q=4g+j][d=16f+r] += P * V ----
            #pragma unroll
            for (int f = 0; f < 8; f++) {
                int d = f * 16 + r;
                #pragma unroll
                for (int kk = 0; kk < 2; kk++) {
                    bf16x8 vf = *(const bf16x8*)(Vt + d * 64 + (((4 * kk + g) ^ (d & 7)) * 8));
                    o_acc[f] = MFMA(pa[kk], vf, o_acc[f]);
                }
            }
        }
    }
    // ---- epilogue ----
    float lO[4];
    #pragma unroll
    for (int j = 0; j < 4; j++) lO[j] = __shfl(l_run, 4 * g + j);
    #pragma unroll
    for (int f = 0; f < 8; f++)
        #pragma unroll
        for (int j = 0; j < 4; j++) {
            int qq = q0w + 4 * g + j;
            int d = f * 16 + r;
            O[((size_t)qq * NH + h) * HD + d] = (bf16)(o_acc[f][j] / lO[j]);
        }
}

// ---------------- launch ----------------
extern "C" void kernel_launch(void* const* d_in, const int* in_sizes, int n_in,
                              void* d_out, int out_size, void* d_ws, size_t ws_size,
                              hipStream_t stream) {
    const int*   pos  = (const int*)d_in[0];
    const float* hid  = (const float*)d_in[1];
    const float* lw   = (const float*)d_in[2];
    const float* qkvw = (const float*)d_in[3];
    const float* qnw  = (const float*)d_in[4];
    const float* knw  = (const float*)d_in[5];
    const float* ow   = (const float*)d_in[6];
    float* out = (float*)d_out;

    char* ws = (char*)d_ws;
    bf16*  qkvw_b = (bf16*)(ws);                          // 16 MB
    bf16*  ow_b   = (bf16*)(ws + (16u << 20));            // 8 MB
    bf16*  normed = (bf16*)(ws + (24u << 20));            // 8 MB
    float* qkvf   = (float*)(ws + (32u << 20));           // 32 MB
    bf16*  qb     = (bf16*)(ws + (64u << 20));            // 8 MB
    bf16*  kb     = (bf16*)(ws + (72u << 20));            // 4 MB
    bf16*  vb     = (bf16*)(ws + (76u << 20));            // 4 MB
    bf16*  ao     = normed;  // reuse: normed is dead after QKV GEMM

    k_f2b<<<4096, 256, 0, stream>>>(qkvw, qkvw_b, 4096 * 2048);
    k_f2b<<<2048, 256, 0, stream>>>(ow, ow_b, 2048 * 2048);
    k_rmsnorm<<<T_N, 256, 0, stream>>>(hid, lw, normed);
    k_gemm_bt<<<dim3(32, 16), 256, 0, stream>>>(normed, qkvw_b, qkvf, 2048, 4096, 2048);
    k_normrope<<<dim3(T_N, 32), 128, 0, stream>>>(qkvf, qnw, knw, pos, qb, kb, vb);
    k_flash<<<dim3(NH, 32), 256, 0, stream>>>(qb, kb, vb, ao);
    k_gemm_bt<<<dim3(16, 16), 256, 0, stream>>>(ao, ow_b, out, 2048, 2048, 2048);
}

// Round 4
// 196.810 us; speedup vs baseline: 1.4111x; 1.0446x over previous
//
#include <hip/hip_runtime.h>
#include <cstdint>
#include <cstddef>

typedef __bf16 bf16;
typedef __attribute__((ext_vector_type(8))) __bf16 bf16x8;
typedef __attribute__((ext_vector_type(4))) __bf16 bf16x4v;
typedef __attribute__((ext_vector_type(4))) float f32x4;
typedef __attribute__((ext_vector_type(4))) short short4v;

#define T_N   2048
#define HID_N 2048
#define NH    16
#define NKV   8
#define HD    128

#define MFMA(a, b, c) __builtin_amdgcn_mfma_f32_16x16x32_bf16((a), (b), (c), 0, 0, 0)

__device__ __forceinline__ f32x4 MFMA16(short4v a, short4v b, f32x4 c) {
#if __has_builtin(__builtin_amdgcn_mfma_f32_16x16x16bf16_1k)
    return __builtin_amdgcn_mfma_f32_16x16x16bf16_1k(a, b, c, 0, 0, 0);
#else
    asm volatile("v_mfma_f32_16x16x16_bf16 %0, %1, %2, %0\n\ts_nop 7\n\ts_nop 7"
                 : "+v"(c) : "v"(a), "v"(b));
    return c;
#endif
}

__device__ __forceinline__ void gl_lds16(const void* g, void* l) {
    __builtin_amdgcn_global_load_lds(
        (const __attribute__((address_space(1))) unsigned int*)g,
        (__attribute__((address_space(3))) unsigned int*)l,
        16, 0, 0);
}

__device__ __forceinline__ uint32_t pk2(float a, float b) {
    union { bf16 h; unsigned short u; } ca, cb;
    ca.h = (bf16)a; cb.h = (bf16)b;
    return ((uint32_t)cb.u << 16) | ca.u;
}

// ---------------- fp32 -> bf16 convert (weights) ----------------
__global__ __launch_bounds__(256) void k_f2b(const float* __restrict__ in,
                                             bf16* __restrict__ out, int n) {
    int i = (blockIdx.x * 256 + threadIdx.x) * 8;
    if (i >= n) return;
    const float4* p = (const float4*)(in + i);
    float4 a = p[0], b = p[1];
    bf16x8 v;
    v[0] = (bf16)a.x; v[1] = (bf16)a.y; v[2] = (bf16)a.z; v[3] = (bf16)a.w;
    v[4] = (bf16)b.x; v[5] = (bf16)b.y; v[6] = (bf16)b.z; v[7] = (bf16)b.w;
    *(bf16x8*)(out + i) = v;
}

// ---------------- hidden RMSNorm -> bf16 ----------------
__global__ __launch_bounds__(256) void k_rmsnorm(const float* __restrict__ x,
                                                 const float* __restrict__ w,
                                                 bf16* __restrict__ out) {
    int row = blockIdx.x, tid = threadIdx.x;
    const float* xr = x + (size_t)row * HID_N;
    float4 a = ((const float4*)xr)[tid * 2];
    float4 b = ((const float4*)xr)[tid * 2 + 1];
    float ss = a.x*a.x + a.y*a.y + a.z*a.z + a.w*a.w
             + b.x*b.x + b.y*b.y + b.z*b.z + b.w*b.w;
    #pragma unroll
    for (int m = 32; m; m >>= 1) ss += __shfl_xor(ss, m);
    __shared__ float red[4];
    if ((tid & 63) == 0) red[tid >> 6] = ss;
    __syncthreads();
    float tot = red[0] + red[1] + red[2] + red[3];
    float rs = rsqrtf(tot * (1.0f / HID_N) + 1e-6f);
    const float4* wr = (const float4*)(w + tid * 8);
    float4 wa = wr[0], wb = wr[1];
    bf16x8 v;
    v[0] = (bf16)(a.x * rs * wa.x); v[1] = (bf16)(a.y * rs * wa.y);
    v[2] = (bf16)(a.z * rs * wa.z); v[3] = (bf16)(a.w * rs * wa.w);
    v[4] = (bf16)(b.x * rs * wb.x); v[5] = (bf16)(b.y * rs * wb.y);
    v[6] = (bf16)(b.z * rs * wb.z); v[7] = (bf16)(b.w * rs * wb.w);
    *(bf16x8*)(out + (size_t)row * HID_N + tid * 8) = v;
}

// ---------------- GEMM: C[M][N] = A[M][K] * B[N][K]^T (bf16 in, fp32 out) ----
__global__ __launch_bounds__(256, 2) void k_gemm_bt(const bf16* __restrict__ A,
                                                    const bf16* __restrict__ B,
                                                    float* __restrict__ C,
                                                    int M, int N, int K) {
    __shared__ __attribute__((aligned(16))) bf16 As[128 * 64];
    __shared__ __attribute__((aligned(16))) bf16 Bs[128 * 64];
    const int tid = threadIdx.x;
    const int lane = tid & 63, wid = tid >> 6;
    const int wm = wid >> 1, wn = wid & 1;
    const int r = lane & 15, g = lane >> 4;
    const size_t bm = (size_t)blockIdx.y * 128, bn = (size_t)blockIdx.x * 128;

    f32x4 acc[4][4] = {};

    const int srow = tid >> 3;
    const int schk = tid & 7;

    for (int k0 = 0; k0 < K; k0 += 64) {
        __syncthreads();
        #pragma unroll
        for (int c = 0; c < 4; c++) {
            int row = c * 32 + srow;
            int ka = (schk ^ (row & 7)) << 3;
            gl_lds16(A + (bm + row) * (size_t)K + k0 + ka,
                     (char*)As + c * 4096 + tid * 16);
            gl_lds16(B + (bn + row) * (size_t)K + k0 + ka,
                     (char*)Bs + c * 4096 + tid * 16);
        }
        __syncthreads();
        #pragma unroll
        for (int kk = 0; kk < 2; kk++) {
            bf16x8 af[4], bfr[4];
            #pragma unroll
            for (int m = 0; m < 4; m++) {
                int row = wm * 64 + m * 16 + r;
                af[m] = *(const bf16x8*)(As + row * 64 + (((kk * 4 + g) ^ (row & 7)) << 3));
            }
            #pragma unroll
            for (int n = 0; n < 4; n++) {
                int row = wn * 64 + n * 16 + r;
                bfr[n] = *(const bf16x8*)(Bs + row * 64 + (((kk * 4 + g) ^ (row & 7)) << 3));
            }
            #pragma unroll
            for (int m = 0; m < 4; m++)
                #pragma unroll
                for (int n = 0; n < 4; n++)
                    acc[m][n] = MFMA(af[m], bfr[n], acc[m][n]);
        }
    }
    #pragma unroll
    for (int m = 0; m < 4; m++)
        #pragma unroll
        for (int n = 0; n < 4; n++)
            #pragma unroll
            for (int j = 0; j < 4; j++) {
                size_t row = bm + wm * 64 + m * 16 + g * 4 + j;
                size_t col = bn + wn * 64 + n * 16 + r;
                C[row * (size_t)N + col] = acc[m][n][j];
            }
}

// ---------------- per-head RMSNorm + RoPE (q,k), bf16 cast (v) ----------------
__global__ __launch_bounds__(128) void k_normrope(const float* __restrict__ qkv,
                                                  const float* __restrict__ qw,
                                                  const float* __restrict__ kw,
                                                  const int* __restrict__ pos,
                                                  bf16* __restrict__ q,
                                                  bf16* __restrict__ k,
                                                  bf16* __restrict__ v) {
    int t = blockIdx.x, hs = blockIdx.y, d = threadIdx.x;
    const float* base = qkv + (size_t)t * 4096;
    if (hs >= 24) {
        int hv = hs - 24;
        v[((size_t)t * NKV + hv) * HD + d] = (bf16)base[3072 + hv * 128 + d];
        return;
    }
    bool isq = hs < 16;
    int h = isq ? hs : hs - 16;
    float x = isq ? base[h * 128 + d] : base[2048 + h * 128 + d];
    float ss = x * x;
    #pragma unroll
    for (int m = 32; m; m >>= 1) ss += __shfl_xor(ss, m);
    __shared__ float red[2];
    if ((d & 63) == 0) red[d >> 6] = ss;
    __syncthreads();
    float rs = rsqrtf((red[0] + red[1]) * (1.0f / HD) + 1e-6f);
    float nx = x * rs * (isq ? qw[d] : kw[d]);
    __shared__ float sh[128];
    sh[d] = nx;
    __syncthreads();
    float other = sh[d ^ 64];
    int j = d & 63;
    float ang = (float)pos[t] * __powf(10000.f, -(float)j * (1.f / 64.f));
    float s, c;
    __sincosf(ang, &s, &c);
    float o = (d < 64) ? (nx * c - other * s) : (nx * c + other * s);
    bf16* dst = isq ? (q + ((size_t)t * NH + h) * HD + d)
                    : (k + ((size_t)t * NKV + h) * HD + d);
    *dst = (bf16)o;
}

// ---------------- flash attention v4 ----------------
// Verified R2 components: K staging (chunk-XOR), swapped QK^T, lane-local
// softmax, Vt[d][k] column staging. New: PV as 16x16x16 MFMAs computing O^T
// (P direct from softmax regs, A = V^T via ds_read_b64 from Vt), depth-1
// prefetch pipeline (stage t+1 issued before compute t), setprio around MFMA.
__global__ __launch_bounds__(256, 2) void k_flash(const bf16* __restrict__ Q,
                                                  const bf16* __restrict__ K,
                                                  const bf16* __restrict__ V,
                                                  bf16* __restrict__ O) {
    __shared__ __attribute__((aligned(16))) bf16 Ks2[2][64 * 128];  // 32 KB
    __shared__ __attribute__((aligned(16))) bf16 Vt2[2][128 * 64];  // 32 KB

    const int tid = threadIdx.x, lane = tid & 63, w = tid >> 6;
    const int r = lane & 15, g = lane >> 4;
    const int h = blockIdx.x, by = blockIdx.y;
    const int qt = (by < 16) ? (2 * by) : (63 - 2 * by);  // zig-zag balance
    const int q0 = qt * 64;
    const int gh = h >> 1;
    const int q0w = q0 + w * 16;

    const int rowk = tid >> 4, posc = tid & 15;  // K staging
    const int vd = tid & 127, vhalf = tid >> 7;  // V staging (column gather)

    // Q fragment (B-operand of QK^T): lane(r,g) holds Q[q0w+r][32ks+8g..]
    bf16x8 qf[4];
    #pragma unroll
    for (int ks = 0; ks < 4; ks++)
        qf[ks] = *(const bf16x8*)(Q + ((size_t)(q0w + r) * NH + h) * HD + ks * 32 + g * 8);

    f32x4 acc[8] = {};  // acc[f][j] = O^T[d=16f+4g+j][q=r]
    float m_run = -1e30f, l_run = 0.f;
    const float scale = 0.08838834764831845f;
    const int nt = qt + 1;

    // ---- prologue: stage tile 0 into buffer 0 ----
    {
        #pragma unroll
        for (int c = 0; c < 4; c++) {
            int row = c * 16 + rowk;
            int srcc = posc ^ (row & 7);
            gl_lds16(K + ((size_t)row * NKV + gh) * HD + srcc * 8,
                     (char*)&Ks2[0][0] + c * 4096 + tid * 16);
        }
        bf16x8 vr[4];
        #pragma unroll
        for (int it = 0; it < 4; it++) {
            int kb = vhalf + it * 2;
            const bf16* src = V + ((size_t)(kb * 8) * NKV + gh) * HD + vd;
            #pragma unroll
            for (int i = 0; i < 8; i++) vr[it][i] = src[(size_t)i * (NKV * HD)];
        }
        #pragma unroll
        for (int it = 0; it < 4; it++) {
            int kb = vhalf + it * 2;
            *(bf16x8*)(&Vt2[0][0] + vd * 64 + ((kb ^ (vd & 7)) * 8)) = vr[it];
        }
        __syncthreads();
    }

    for (int t = 0; t < nt; ++t) {
        const int b = t & 1;
        const int kv0 = t * 64;
        const bool pf = (t + 1 < nt);
        bf16x8 vr[4];
        // ---- issue stage for t+1 (latency hides under compute of t) ----
        if (pf) {
            const int kv1 = kv0 + 64;
            #pragma unroll
            for (int c = 0; c < 4; c++) {
                int row = c * 16 + rowk;
                int srcc = posc ^ (row & 7);
                gl_lds16(K + ((size_t)(kv1 + row) * NKV + gh) * HD + srcc * 8,
                         (char*)&Ks2[0][0] + (b ^ 1) * 16384 + c * 4096 + tid * 16);
            }
            #pragma unroll
            for (int it = 0; it < 4; it++) {
                int kb = vhalf + it * 2;
                const bf16* src = V + ((size_t)(kv1 + kb * 8) * NKV + gh) * HD + vd;
                #pragma unroll
                for (int i = 0; i < 8; i++) vr[it][i] = src[(size_t)i * (NKV * HD)];
            }
        }
        // ---- compute tile t from buffer b ----
        {
            const bf16* Kb = &Ks2[b][0];
            const char* Vb = (const char*)&Vt2[b][0];
            float sc[4][4];
            __builtin_amdgcn_s_setprio(1);
            #pragma unroll
            for (int t4 = 0; t4 < 4; t4++) {
                f32x4 S = {};
                #pragma unroll
                for (int ks = 0; ks < 4; ks++) {
                    int row = t4 * 16 + r;
                    bf16x8 kf = *(const bf16x8*)(Kb + row * 128 + (((4 * ks + g) ^ (row & 7)) * 8));
                    S = MFMA(kf, qf[ks], S);
                }
                #pragma unroll
                for (int j = 0; j < 4; j++) {
                    int kg = kv0 + t4 * 16 + 4 * g + j;
                    sc[t4][j] = (kg <= q0w + r) ? S[j] * scale : -1e30f;
                }
            }
            __builtin_amdgcn_s_setprio(0);
            // online softmax (q = r lane-local; reduce across g via 2 shfl)
            float mx = sc[0][0];
            #pragma unroll
            for (int t4 = 0; t4 < 4; t4++)
                #pragma unroll
                for (int j = 0; j < 4; j++) mx = fmaxf(mx, sc[t4][j]);
            mx = fmaxf(mx, __shfl_xor(mx, 16));
            mx = fmaxf(mx, __shfl_xor(mx, 32));
            float mn = fmaxf(m_run, mx);
            float alpha = __expf(m_run - mn);
            m_run = mn;
            float rsum = 0.f;
            #pragma unroll
            for (int t4 = 0; t4 < 4; t4++)
                #pragma unroll
                for (int j = 0; j < 4; j++) {
                    sc[t4][j] = __expf(sc[t4][j] - mn);
                    rsum += sc[t4][j];
                }
            rsum += __shfl_xor(rsum, 16);
            rsum += __shfl_xor(rsum, 32);
            l_run = l_run * alpha + rsum;
            // rescale O^T (col q=r is lane-local -> scalar alpha, no shuffles)
            #pragma unroll
            for (int f = 0; f < 8; f++)
                #pragma unroll
                for (int j = 0; j < 4; j++) acc[f][j] *= alpha;
            // P -> 16x16x16 B-operands directly: pb[t4] = P[q=r][k=16t4+4g+i]
            union PB { uint32_t u[2]; short4v s; };
            PB pbu[4];
            #pragma unroll
            for (int t4 = 0; t4 < 4; t4++) {
                pbu[t4].u[0] = pk2(sc[t4][0], sc[t4][1]);
                pbu[t4].u[1] = pk2(sc[t4][2], sc[t4][3]);
            }
            // PV: O^T[d][q] += V^T[d][k] * P^T[k][q]; A = V^T from Vt (b64 reads)
            __builtin_amdgcn_s_setprio(1);
            #pragma unroll
            for (int f = 0; f < 8; f++) {
                #pragma unroll
                for (int t4 = 0; t4 < 4; t4++) {
                    short4v vf = *(const short4v*)(Vb + f * 2048 + r * 128 +
                                  (((2 * t4 + (g >> 1)) ^ (r & 7)) * 16) + (g & 1) * 8);
                    acc[f] = MFMA16(vf, pbu[t4].s, acc[f]);
                }
            }
            __builtin_amdgcn_s_setprio(0);
        }
        // ---- write prefetched V columns into buffer b^1, then barrier ----
        if (pf) {
            #pragma unroll
            for (int it = 0; it < 4; it++) {
                int kb = vhalf + it * 2;
                *(bf16x8*)(&Vt2[0][0] + (b ^ 1) * 8192 + vd * 64 + ((kb ^ (vd & 7)) * 8)) = vr[it];
            }
        }
        __syncthreads();
    }
    // ---- epilogue: lane-local divide, 8B vector stores ----
    float inv_l = 1.0f / l_run;
    #pragma unroll
    for (int f = 0; f < 8; f++) {
        bf16x4v ov;
        #pragma unroll
        for (int j = 0; j < 4; j++) ov[j] = (bf16)(acc[f][j] * inv_l);
        *(bf16x4v*)(O + ((size_t)(q0w + r) * NH + h) * HD + f * 16 + 4 * g) = ov;
    }
}

// ---------------- launch ----------------
extern "C" void kernel_launch(void* const* d_in, const int* in_sizes, int n_in,
                              void* d_out, int out_size, void* d_ws, size_t ws_size,
                              hipStream_t stream) {
    const int*   pos  = (const int*)d_in[0];
    const float* hid  = (const float*)d_in[1];
    const float* lw   = (const float*)d_in[2];
    const float* qkvw = (const float*)d_in[3];
    const float* qnw  = (const float*)d_in[4];
    const float* knw  = (const float*)d_in[5];
    const float* ow   = (const float*)d_in[6];
    float* out = (float*)d_out;

    char* ws = (char*)d_ws;
    bf16*  qkvw_b = (bf16*)(ws);
    bf16*  ow_b   = (bf16*)(ws + (16u << 20));
    bf16*  normed = (bf16*)(ws + (24u << 20));
    float* qkvf   = (float*)(ws + (32u << 20));
    bf16*  qb     = (bf16*)(ws + (64u << 20));
    bf16*  kb     = (bf16*)(ws + (72u << 20));
    bf16*  vb     = (bf16*)(ws + (76u << 20));
    bf16*  ao     = normed;  // reuse: normed dead after QKV GEMM

    k_f2b<<<4096, 256, 0, stream>>>(qkvw, qkvw_b, 4096 * 2048);
    k_f2b<<<2048, 256, 0, stream>>>(ow, ow_b, 2048 * 2048);
    k_rmsnorm<<<T_N, 256, 0, stream>>>(hid, lw, normed);
    k_gemm_bt<<<dim3(32, 16), 256, 0, stream>>>(normed, qkvw_b, qkvf, 2048, 4096, 2048);
    k_normrope<<<dim3(T_N, 32), 128, 0, stream>>>(qkvf, qnw, knw, pos, qb, kb, vb);
    k_flash<<<dim3(NH, 32), 256, 0, stream>>>(qb, kb, vb, ao);
    k_gemm_bt<<<dim3(16, 16), 256, 0, stream>>>(ao, ow_b, out, 2048, 2048, 2048);
}

// Round 5
// 185.747 us; speedup vs baseline: 1.4952x; 1.0596x over previous
//
#include <hip/hip_runtime.h>
#include <cstdint>
#include <cstddef>

typedef __bf16 bf16;
typedef __attribute__((ext_vector_type(8))) __bf16 bf16x8;
typedef __attribute__((ext_vector_type(4))) __bf16 bf16x4v;
typedef __attribute__((ext_vector_type(4))) float f32x4;
typedef __attribute__((ext_vector_type(4))) short short4v;

#define T_N   2048
#define HID_N 2048
#define NH    16
#define NKV   8
#define HD    128

#define MFMA(a, b, c) __builtin_amdgcn_mfma_f32_16x16x32_bf16((a), (b), (c), 0, 0, 0)

__device__ __forceinline__ f32x4 MFMA16(short4v a, short4v b, f32x4 c) {
#if __has_builtin(__builtin_amdgcn_mfma_f32_16x16x16bf16_1k)
    return __builtin_amdgcn_mfma_f32_16x16x16bf16_1k(a, b, c, 0, 0, 0);
#else
    asm volatile("v_mfma_f32_16x16x16_bf16 %0, %1, %2, %0\n\ts_nop 7\n\ts_nop 7"
                 : "+v"(c) : "v"(a), "v"(b));
    return c;
#endif
}

__device__ __forceinline__ void gl_lds16(const void* g, void* l) {
    __builtin_amdgcn_global_load_lds(
        (const __attribute__((address_space(1))) unsigned int*)g,
        (__attribute__((address_space(3))) unsigned int*)l,
        16, 0, 0);
}

__device__ __forceinline__ uint32_t pk2(float a, float b) {
    union { bf16 h; unsigned short u; } ca, cb;
    ca.h = (bf16)a; cb.h = (bf16)b;
    return ((uint32_t)cb.u << 16) | ca.u;
}

// ---------------- fp32 -> bf16 convert (weights) ----------------
__global__ __launch_bounds__(256) void k_f2b(const float* __restrict__ in,
                                             bf16* __restrict__ out, int n) {
    int i = (blockIdx.x * 256 + threadIdx.x) * 8;
    if (i >= n) return;
    const float4* p = (const float4*)(in + i);
    float4 a = p[0], b = p[1];
    bf16x8 v;
    v[0] = (bf16)a.x; v[1] = (bf16)a.y; v[2] = (bf16)a.z; v[3] = (bf16)a.w;
    v[4] = (bf16)b.x; v[5] = (bf16)b.y; v[6] = (bf16)b.z; v[7] = (bf16)b.w;
    *(bf16x8*)(out + i) = v;
}

// ---------------- hidden RMSNorm -> bf16 ----------------
__global__ __launch_bounds__(256) void k_rmsnorm(const float* __restrict__ x,
                                                 const float* __restrict__ w,
                                                 bf16* __restrict__ out) {
    int row = blockIdx.x, tid = threadIdx.x;
    const float* xr = x + (size_t)row * HID_N;
    float4 a = ((const float4*)xr)[tid * 2];
    float4 b = ((const float4*)xr)[tid * 2 + 1];
    float ss = a.x*a.x + a.y*a.y + a.z*a.z + a.w*a.w
             + b.x*b.x + b.y*b.y + b.z*b.z + b.w*b.w;
    #pragma unroll
    for (int m = 32; m; m >>= 1) ss += __shfl_xor(ss, m);
    __shared__ float red[4];
    if ((tid & 63) == 0) red[tid >> 6] = ss;
    __syncthreads();
    float tot = red[0] + red[1] + red[2] + red[3];
    float rs = rsqrtf(tot * (1.0f / HID_N) + 1e-6f);
    const float4* wr = (const float4*)(w + tid * 8);
    float4 wa = wr[0], wb = wr[1];
    bf16x8 v;
    v[0] = (bf16)(a.x * rs * wa.x); v[1] = (bf16)(a.y * rs * wa.y);
    v[2] = (bf16)(a.z * rs * wa.z); v[3] = (bf16)(a.w * rs * wa.w);
    v[4] = (bf16)(b.x * rs * wb.x); v[5] = (bf16)(b.y * rs * wb.y);
    v[6] = (bf16)(b.z * rs * wb.z); v[7] = (bf16)(b.w * rs * wb.w);
    *(bf16x8*)(out + (size_t)row * HID_N + tid * 8) = v;
}

// ---------------- GEMM: C[M][N] = A[M][K] * B[N][K]^T (bf16 in, fp32 out) ----
__global__ __launch_bounds__(256, 2) void k_gemm_bt(const bf16* __restrict__ A,
                                                    const bf16* __restrict__ B,
                                                    float* __restrict__ C,
                                                    int M, int N, int K) {
    __shared__ __attribute__((aligned(16))) bf16 As[128 * 64];
    __shared__ __attribute__((aligned(16))) bf16 Bs[128 * 64];
    const int tid = threadIdx.x;
    const int lane = tid & 63, wid = tid >> 6;
    const int wm = wid >> 1, wn = wid & 1;
    const int r = lane & 15, g = lane >> 4;
    const size_t bm = (size_t)blockIdx.y * 128, bn = (size_t)blockIdx.x * 128;

    f32x4 acc[4][4] = {};

    const int srow = tid >> 3;
    const int schk = tid & 7;

    for (int k0 = 0; k0 < K; k0 += 64) {
        __syncthreads();
        #pragma unroll
        for (int c = 0; c < 4; c++) {
            int row = c * 32 + srow;
            int ka = (schk ^ (row & 7)) << 3;
            gl_lds16(A + (bm + row) * (size_t)K + k0 + ka,
                     (char*)As + c * 4096 + tid * 16);
            gl_lds16(B + (bn + row) * (size_t)K + k0 + ka,
                     (char*)Bs + c * 4096 + tid * 16);
        }
        __syncthreads();
        #pragma unroll
        for (int kk = 0; kk < 2; kk++) {
            bf16x8 af[4], bfr[4];
            #pragma unroll
            for (int m = 0; m < 4; m++) {
                int row = wm * 64 + m * 16 + r;
                af[m] = *(const bf16x8*)(As + row * 64 + (((kk * 4 + g) ^ (row & 7)) << 3));
            }
            #pragma unroll
            for (int n = 0; n < 4; n++) {
                int row = wn * 64 + n * 16 + r;
                bfr[n] = *(const bf16x8*)(Bs + row * 64 + (((kk * 4 + g) ^ (row & 7)) << 3));
            }
            #pragma unroll
            for (int m = 0; m < 4; m++)
                #pragma unroll
                for (int n = 0; n < 4; n++)
                    acc[m][n] = MFMA(af[m], bfr[n], acc[m][n]);
        }
    }
    #pragma unroll
    for (int m = 0; m < 4; m++)
        #pragma unroll
        for (int n = 0; n < 4; n++)
            #pragma unroll
            for (int j = 0; j < 4; j++) {
                size_t row = bm + wm * 64 + m * 16 + g * 4 + j;
                size_t col = bn + wn * 64 + n * 16 + r;
                C[row * (size_t)N + col] = acc[m][n][j];
            }
}

// ---------------- per-head RMSNorm + RoPE (q,k), bf16 cast (v) ----------------
__global__ __launch_bounds__(128) void k_normrope(const float* __restrict__ qkv,
                                                  const float* __restrict__ qw,
                                                  const float* __restrict__ kw,
                                                  const int* __restrict__ pos,
                                                  bf16* __restrict__ q,
                                                  bf16* __restrict__ k,
                                                  bf16* __restrict__ v) {
    int t = blockIdx.x, hs = blockIdx.y, d = threadIdx.x;
    const float* base = qkv + (size_t)t * 4096;
    if (hs >= 24) {
        int hv = hs - 24;
        v[((size_t)t * NKV + hv) * HD + d] = (bf16)base[3072 + hv * 128 + d];
        return;
    }
    bool isq = hs < 16;
    int h = isq ? hs : hs - 16;
    float x = isq ? base[h * 128 + d] : base[2048 + h * 128 + d];
    float ss = x * x;
    #pragma unroll
    for (int m = 32; m; m >>= 1) ss += __shfl_xor(ss, m);
    __shared__ float red[2];
    if ((d & 63) == 0) red[d >> 6] = ss;
    __syncthreads();
    float rs = rsqrtf((red[0] + red[1]) * (1.0f / HD) + 1e-6f);
    float nx = x * rs * (isq ? qw[d] : kw[d]);
    __shared__ float sh[128];
    sh[d] = nx;
    __syncthreads();
    float other = sh[d ^ 64];
    int j = d & 63;
    float ang = (float)pos[t] * __powf(10000.f, -(float)j * (1.f / 64.f));
    float s, c;
    __sincosf(ang, &s, &c);
    float o = (d < 64) ? (nx * c - other * s) : (nx * c + other * s);
    bf16* dst = isq ? (q + ((size_t)t * NH + h) * HD + d)
                    : (k + ((size_t)t * NKV + h) * HD + d);
    *dst = (bf16)o;
}

// ---------------- flash attention v5: kv-split (flash-decoding) ----------------
// grid (16 heads, 80): y enumerates (qt, chunk) pairs; chunk = 8 kv-tiles (512 keys).
// Each block computes a normalized partial O (bf16) + (m,l) for its chunk.
// Inner tile compute identical to verified R4 (swapped QK^T, O^T 16x16x16 PV).
// LDS 48KB: K double-buffered (32K) + single V buffer (16K), 2 barriers/tile.
__global__ __launch_bounds__(256, 3) void k_flash(const bf16* __restrict__ Q,
                                                  const bf16* __restrict__ K,
                                                  const bf16* __restrict__ V,
                                                  bf16* __restrict__ On,
                                                  float* __restrict__ ml) {
    __shared__ __attribute__((aligned(16))) bf16 Ks2[2][64 * 128];  // 32 KB
    __shared__ __attribute__((aligned(16))) bf16 Vt[128 * 64];      // 16 KB

    const int tid = threadIdx.x, lane = tid & 63, w = tid >> 6;
    const int r = lane & 15, g = lane >> 4;
    const int h = blockIdx.x, y = blockIdx.y;
    int ci, qt;
    if (y < 32)      { ci = 0; qt = y; }
    else if (y < 56) { ci = 1; qt = y - 24; }
    else if (y < 72) { ci = 2; qt = y - 40; }
    else             { ci = 3; qt = y - 48; }
    const int c0 = ci * 8;                       // first kv-tile of chunk
    const int ntl = min(qt + 1 - c0, 8);         // tiles in this chunk (>=1)
    const int q0 = qt * 64;
    const int gh = h >> 1;
    const int q0w = q0 + w * 16;

    const int rowk = tid >> 4, posc = tid & 15;  // K staging
    const int vd = tid & 127, vhalf = tid >> 7;  // V staging (column gather)

    // Q fragment (B-operand of QK^T): lane(r,g) holds Q[q0w+r][32ks+8g..]
    bf16x8 qf[4];
    #pragma unroll
    for (int ks = 0; ks < 4; ks++)
        qf[ks] = *(const bf16x8*)(Q + ((size_t)(q0w + r) * NH + h) * HD + ks * 32 + g * 8);

    f32x4 acc[8] = {};  // acc[f][j] = O^T[d=16f+4g+j][q=r]
    float m_run = -1e30f, l_run = 0.f;
    const float scale = 0.08838834764831845f;

    // ---- prologue: stage tile c0 ----
    {
        const int kv0 = c0 * 64;
        #pragma unroll
        for (int c = 0; c < 4; c++) {
            int row = c * 16 + rowk;
            int srcc = posc ^ (row & 7);
            gl_lds16(K + ((size_t)(kv0 + row) * NKV + gh) * HD + srcc * 8,
                     (char*)&Ks2[0][0] + c * 4096 + tid * 16);
        }
        bf16x8 vr[4];
        #pragma unroll
        for (int it = 0; it < 4; it++) {
            int kb = vhalf + it * 2;
            const bf16* src = V + ((size_t)(kv0 + kb * 8) * NKV + gh) * HD + vd;
            #pragma unroll
            for (int i = 0; i < 8; i++) vr[it][i] = src[(size_t)i * (NKV * HD)];
        }
        #pragma unroll
        for (int it = 0; it < 4; it++) {
            int kb = vhalf + it * 2;
            *(bf16x8*)(&Vt[0] + vd * 64 + ((kb ^ (vd & 7)) * 8)) = vr[it];
        }
        __syncthreads();
    }

    for (int t = 0; t < ntl; ++t) {
        const int b = t & 1;
        const int kv0 = (c0 + t) * 64;
        const bool pf = (t + 1 < ntl);
        bf16x8 vr[4];
        // ---- issue stage for t+1 (latency hides under compute of t) ----
        if (pf) {
            const int kv1 = kv0 + 64;
            #pragma unroll
            for (int c = 0; c < 4; c++) {
                int row = c * 16 + rowk;
                int srcc = posc ^ (row & 7);
                gl_lds16(K + ((size_t)(kv1 + row) * NKV + gh) * HD + srcc * 8,
                         (char*)&Ks2[0][0] + (b ^ 1) * 16384 + c * 4096 + tid * 16);
            }
            #pragma unroll
            for (int it = 0; it < 4; it++) {
                int kb = vhalf + it * 2;
                const bf16* src = V + ((size_t)(kv1 + kb * 8) * NKV + gh) * HD + vd;
                #pragma unroll
                for (int i = 0; i < 8; i++) vr[it][i] = src[(size_t)i * (NKV * HD)];
            }
        }
        // ---- compute tile t (identical to verified R4 inner code) ----
        if (kv0 <= q0w + 15) {
            const bf16* Kb = &Ks2[b][0];
            const char* Vb = (const char*)&Vt[0];
            float sc[4][4];
            __builtin_amdgcn_s_setprio(1);
            #pragma unroll
            for (int t4 = 0; t4 < 4; t4++) {
                f32x4 S = {};
                #pragma unroll
                for (int ks = 0; ks < 4; ks++) {
                    int row = t4 * 16 + r;
                    bf16x8 kf = *(const bf16x8*)(Kb + row * 128 + (((4 * ks + g) ^ (row & 7)) * 8));
                    S = MFMA(kf, qf[ks], S);
                }
                #pragma unroll
                for (int j = 0; j < 4; j++) {
                    int kg = kv0 + t4 * 16 + 4 * g + j;
                    sc[t4][j] = (kg <= q0w + r) ? S[j] * scale : -1e30f;
                }
            }
            __builtin_amdgcn_s_setprio(0);
            float mx = sc[0][0];
            #pragma unroll
            for (int t4 = 0; t4 < 4; t4++)
                #pragma unroll
                for (int j = 0; j < 4; j++) mx = fmaxf(mx, sc[t4][j]);
            mx = fmaxf(mx, __shfl_xor(mx, 16));
            mx = fmaxf(mx, __shfl_xor(mx, 32));
            float mn = fmaxf(m_run, mx);
            float alpha = __expf(m_run - mn);
            m_run = mn;
            float rsum = 0.f;
            #pragma unroll
            for (int t4 = 0; t4 < 4; t4++)
                #pragma unroll
                for (int j = 0; j < 4; j++) {
                    sc[t4][j] = __expf(sc[t4][j] - mn);
                    rsum += sc[t4][j];
                }
            rsum += __shfl_xor(rsum, 16);
            rsum += __shfl_xor(rsum, 32);
            l_run = l_run * alpha + rsum;
            #pragma unroll
            for (int f = 0; f < 8; f++)
                #pragma unroll
                for (int j = 0; j < 4; j++) acc[f][j] *= alpha;
            union PB { uint32_t u[2]; short4v s; };
            PB pbu[4];
            #pragma unroll
            for (int t4 = 0; t4 < 4; t4++) {
                pbu[t4].u[0] = pk2(sc[t4][0], sc[t4][1]);
                pbu[t4].u[1] = pk2(sc[t4][2], sc[t4][3]);
            }
            __builtin_amdgcn_s_setprio(1);
            #pragma unroll
            for (int f = 0; f < 8; f++) {
                #pragma unroll
                for (int t4 = 0; t4 < 4; t4++) {
                    short4v vf = *(const short4v*)(Vb + f * 2048 + r * 128 +
                                  (((2 * t4 + (g >> 1)) ^ (r & 7)) * 16) + (g & 1) * 8);
                    acc[f] = MFMA16(vf, pbu[t4].s, acc[f]);
                }
            }
            __builtin_amdgcn_s_setprio(0);
        }
        // ---- publish prefetched V into the single V buffer ----
        if (pf) {
            __syncthreads();  // all waves done reading Vt (and Ks2[b]); drains vmem
            #pragma unroll
            for (int it = 0; it < 4; it++) {
                int kb = vhalf + it * 2;
                *(bf16x8*)(&Vt[0] + vd * 64 + ((kb ^ (vd & 7)) * 8)) = vr[it];
            }
            __syncthreads();  // Vt writes visible
        }
    }
    // ---- epilogue: write normalized partial (bf16) + m,l ----
    const int lr = w * 16 + r;
    float inv_l = 1.0f / l_run;
    bf16* Ob = On + ((size_t)(h * 80 + y)) * 8192 + lr * 128;
    #pragma unroll
    for (int f = 0; f < 8; f++) {
        bf16x4v ov;
        #pragma unroll
        for (int j = 0; j < 4; j++) ov[j] = (bf16)(acc[f][j] * inv_l);
        *(bf16x4v*)(Ob + f * 16 + 4 * g) = ov;
    }
    if (g == 0) {
        float* mlp = ml + ((size_t)(h * 80 + y)) * 128;
        mlp[lr] = m_run;
        mlp[64 + lr] = l_run;
    }
}

// ---------------- combine partials ----------------
__global__ __launch_bounds__(256) void k_comb(const bf16* __restrict__ On,
                                              const float* __restrict__ ml,
                                              bf16* __restrict__ ao) {
    const int h = blockIdx.x, qt = blockIdx.y;
    const int lr = threadIdx.x & 63, db = threadIdx.x >> 6;
    const int nc = 1 + (qt >= 8) + (qt >= 16) + (qt >= 24);
    const int ys[4] = {qt, qt + 24, qt + 40, qt + 48};
    float mi[4], li[4], wi[4];
    float mstar = -1e30f;
    for (int i = 0; i < 4; i++) {
        if (i < nc) {
            const float* p = ml + ((size_t)(h * 80 + ys[i])) * 128;
            mi[i] = p[lr]; li[i] = p[64 + lr];
            mstar = fmaxf(mstar, mi[i]);
        }
    }
    float wsum = 0.f;
    for (int i = 0; i < 4; i++) {
        if (i < nc) { wi[i] = li[i] * __expf(mi[i] - mstar); wsum += wi[i]; }
        else wi[i] = 0.f;
    }
    float inv = 1.f / wsum;
    for (int i = 0; i < 4; i++) wi[i] *= inv;
    const int q = qt * 64 + lr;
    #pragma unroll
    for (int dd = 0; dd < 4; dd++) {
        int d0 = db * 32 + dd * 8;
        float o[8] = {};
        for (int i = 0; i < 4; i++) {
            if (i < nc) {
                bf16x8 v = *(const bf16x8*)(On + ((size_t)(h * 80 + ys[i])) * 8192 + lr * 128 + d0);
                #pragma unroll
                for (int j = 0; j < 8; j++) o[j] += wi[i] * (float)v[j];
            }
        }
        bf16x8 ov;
        #pragma unroll
        for (int j = 0; j < 8; j++) ov[j] = (bf16)o[j];
        *(bf16x8*)(ao + ((size_t)q * NH + h) * HD + d0) = ov;
    }
}

// ---------------- launch ----------------
extern "C" void kernel_launch(void* const* d_in, const int* in_sizes, int n_in,
                              void* d_out, int out_size, void* d_ws, size_t ws_size,
                              hipStream_t stream) {
    const int*   pos  = (const int*)d_in[0];
    const float* hid  = (const float*)d_in[1];
    const float* lw   = (const float*)d_in[2];
    const float* qkvw = (const float*)d_in[3];
    const float* qnw  = (const float*)d_in[4];
    const float* knw  = (const float*)d_in[5];
    const float* ow   = (const float*)d_in[6];
    float* out = (float*)d_out;

    char* ws = (char*)d_ws;
    bf16*  qkvw_b = (bf16*)(ws);                   // 0..16 MB
    bf16*  ow_b   = (bf16*)(ws + (16u << 20));     // 16..24 MB
    bf16*  normed = (bf16*)(ws + (24u << 20));     // 24..32 MB (reused as ao)
    float* qkvf   = (float*)(ws + (32u << 20));    // 32..64 MB (reused: On+ml)
    bf16*  qb     = (bf16*)(ws + (64u << 20));     // 64..72 MB
    bf16*  kb     = (bf16*)(ws + (72u << 20));     // 72..76 MB
    bf16*  vb     = (bf16*)(ws + (76u << 20));     // 76..80 MB
    bf16*  ao     = normed;                        // normed dead after QKV GEMM
    bf16*  On     = (bf16*)(ws + (32u << 20));     // 16*80*8192*2B = 20.97 MB
    float* ml     = (float*)(ws + (54u << 20));    // 16*80*128*4B = 0.66 MB

    k_f2b<<<4096, 256, 0, stream>>>(qkvw, qkvw_b, 4096 * 2048);
    k_f2b<<<2048, 256, 0, stream>>>(ow, ow_b, 2048 * 2048);
    k_rmsnorm<<<T_N, 256, 0, stream>>>(hid, lw, normed);
    k_gemm_bt<<<dim3(32, 16), 256, 0, stream>>>(normed, qkvw_b, qkvf, 2048, 4096, 2048);
    k_normrope<<<dim3(T_N, 32), 128, 0, stream>>>(qkvf, qnw, knw, pos, qb, kb, vb);
    k_flash<<<dim3(NH, 80), 256, 0, stream>>>(qb, kb, vb, On, ml);
    k_comb<<<dim3(NH, 32), 256, 0, stream>>>(On, ml, ao);
    k_gemm_bt<<<dim3(16, 16), 256, 0, stream>>>(ao, ow_b, out, 2048, 2048, 2048);
}

// Round 6
// 185.056 us; speedup vs baseline: 1.5007x; 1.0037x over previous
//
#include <hip/hip_runtime.h>
#include <cstdint>
#include <cstddef>

typedef __bf16 bf16;
typedef __attribute__((ext_vector_type(8))) __bf16 bf16x8;
typedef __attribute__((ext_vector_type(4))) __bf16 bf16x4v;
typedef __attribute__((ext_vector_type(4))) float f32x4;
typedef __attribute__((ext_vector_type(4))) short short4v;

#define T_N   2048
#define HID_N 2048
#define NH    16
#define NKV   8
#define HD    128

#define MFMA(a, b, c) __builtin_amdgcn_mfma_f32_16x16x32_bf16((a), (b), (c), 0, 0, 0)

__device__ __forceinline__ f32x4 MFMA16(short4v a, short4v b, f32x4 c) {
#if __has_builtin(__builtin_amdgcn_mfma_f32_16x16x16bf16_1k)
    return __builtin_amdgcn_mfma_f32_16x16x16bf16_1k(a, b, c, 0, 0, 0);
#else
    asm volatile("v_mfma_f32_16x16x16_bf16 %0, %1, %2, %0\n\ts_nop 7\n\ts_nop 7"
                 : "+v"(c) : "v"(a), "v"(b));
    return c;
#endif
}

__device__ __forceinline__ void gl_lds16(const void* g, void* l) {
    __builtin_amdgcn_global_load_lds(
        (const __attribute__((address_space(1))) unsigned int*)g,
        (__attribute__((address_space(3))) unsigned int*)l,
        16, 0, 0);
}

__device__ __forceinline__ uint32_t pk2(float a, float b) {
    union { bf16 h; unsigned short u; } ca, cb;
    ca.h = (bf16)a; cb.h = (bf16)b;
    return ((uint32_t)cb.u << 16) | ca.u;
}

// ---------------- fp32 -> bf16 convert (weights) ----------------
__global__ __launch_bounds__(256) void k_f2b(const float* __restrict__ in,
                                             bf16* __restrict__ out, int n) {
    int i = (blockIdx.x * 256 + threadIdx.x) * 8;
    if (i >= n) return;
    const float4* p = (const float4*)(in + i);
    float4 a = p[0], b = p[1];
    bf16x8 v;
    v[0] = (bf16)a.x; v[1] = (bf16)a.y; v[2] = (bf16)a.z; v[3] = (bf16)a.w;
    v[4] = (bf16)b.x; v[5] = (bf16)b.y; v[6] = (bf16)b.z; v[7] = (bf16)b.w;
    *(bf16x8*)(out + i) = v;
}

// ---------------- hidden RMSNorm -> bf16 ----------------
__global__ __launch_bounds__(256) void k_rmsnorm(const float* __restrict__ x,
                                                 const float* __restrict__ w,
                                                 bf16* __restrict__ out) {
    int row = blockIdx.x, tid = threadIdx.x;
    const float* xr = x + (size_t)row * HID_N;
    float4 a = ((const float4*)xr)[tid * 2];
    float4 b = ((const float4*)xr)[tid * 2 + 1];
    float ss = a.x*a.x + a.y*a.y + a.z*a.z + a.w*a.w
             + b.x*b.x + b.y*b.y + b.z*b.z + b.w*b.w;
    #pragma unroll
    for (int m = 32; m; m >>= 1) ss += __shfl_xor(ss, m);
    __shared__ float red[4];
    if ((tid & 63) == 0) red[tid >> 6] = ss;
    __syncthreads();
    float tot = red[0] + red[1] + red[2] + red[3];
    float rs = rsqrtf(tot * (1.0f / HID_N) + 1e-6f);
    const float4* wr = (const float4*)(w + tid * 8);
    float4 wa = wr[0], wb = wr[1];
    bf16x8 v;
    v[0] = (bf16)(a.x * rs * wa.x); v[1] = (bf16)(a.y * rs * wa.y);
    v[2] = (bf16)(a.z * rs * wa.z); v[3] = (bf16)(a.w * rs * wa.w);
    v[4] = (bf16)(b.x * rs * wb.x); v[5] = (bf16)(b.y * rs * wb.y);
    v[6] = (bf16)(b.z * rs * wb.z); v[7] = (bf16)(b.w * rs * wb.w);
    *(bf16x8*)(out + (size_t)row * HID_N + tid * 8) = v;
}

// ---------------- GEMM: C[M][N] = A[M][K] * B[N][K]^T (bf16 in, fp32 out) ----
__global__ __launch_bounds__(256, 3) void k_gemm_bt(const bf16* __restrict__ A,
                                                    const bf16* __restrict__ B,
                                                    float* __restrict__ C,
                                                    int M, int N, int K) {
    __shared__ __attribute__((aligned(16))) bf16 As[128 * 64];
    __shared__ __attribute__((aligned(16))) bf16 Bs[128 * 64];
    const int tid = threadIdx.x;
    const int lane = tid & 63, wid = tid >> 6;
    const int wm = wid >> 1, wn = wid & 1;
    const int r = lane & 15, g = lane >> 4;
    const size_t bm = (size_t)blockIdx.y * 128, bn = (size_t)blockIdx.x * 128;

    f32x4 acc[4][4] = {};

    const int srow = tid >> 3;
    const int schk = tid & 7;

    for (int k0 = 0; k0 < K; k0 += 64) {
        __syncthreads();
        #pragma unroll
        for (int c = 0; c < 4; c++) {
            int row = c * 32 + srow;
            int ka = (schk ^ (row & 7)) << 3;
            gl_lds16(A + (bm + row) * (size_t)K + k0 + ka,
                     (char*)As + c * 4096 + tid * 16);
            gl_lds16(B + (bn + row) * (size_t)K + k0 + ka,
                     (char*)Bs + c * 4096 + tid * 16);
        }
        __syncthreads();
        #pragma unroll
        for (int kk = 0; kk < 2; kk++) {
            bf16x8 af[4], bfr[4];
            #pragma unroll
            for (int m = 0; m < 4; m++) {
                int row = wm * 64 + m * 16 + r;
                af[m] = *(const bf16x8*)(As + row * 64 + (((kk * 4 + g) ^ (row & 7)) << 3));
            }
            #pragma unroll
            for (int n = 0; n < 4; n++) {
                int row = wn * 64 + n * 16 + r;
                bfr[n] = *(const bf16x8*)(Bs + row * 64 + (((kk * 4 + g) ^ (row & 7)) << 3));
            }
            #pragma unroll
            for (int m = 0; m < 4; m++)
                #pragma unroll
                for (int n = 0; n < 4; n++)
                    acc[m][n] = MFMA(af[m], bfr[n], acc[m][n]);
        }
    }
    #pragma unroll
    for (int m = 0; m < 4; m++)
        #pragma unroll
        for (int n = 0; n < 4; n++)
            #pragma unroll
            for (int j = 0; j < 4; j++) {
                size_t row = bm + wm * 64 + m * 16 + g * 4 + j;
                size_t col = bn + wn * 64 + n * 16 + r;
                C[row * (size_t)N + col] = acc[m][n][j];
            }
}

// ---------------- QKV GEMM variant: bf16 out, v routed to final layout ----------
// C cols [0,3072) -> qkv3[row][col] (q,k); cols [3072,4096) -> vb[row*1024+col-3072].
__global__ __launch_bounds__(256, 3) void k_gemm_qkv(const bf16* __restrict__ A,
                                                     const bf16* __restrict__ B,
                                                     bf16* __restrict__ qkv3,
                                                     bf16* __restrict__ vb) {
    const int K = HID_N;
    __shared__ __attribute__((aligned(16))) bf16 As[128 * 64];
    __shared__ __attribute__((aligned(16))) bf16 Bs[128 * 64];
    const int tid = threadIdx.x;
    const int lane = tid & 63, wid = tid >> 6;
    const int wm = wid >> 1, wn = wid & 1;
    const int r = lane & 15, g = lane >> 4;
    const size_t bm = (size_t)blockIdx.y * 128, bn = (size_t)blockIdx.x * 128;

    f32x4 acc[4][4] = {};
    const int srow = tid >> 3;
    const int schk = tid & 7;

    for (int k0 = 0; k0 < K; k0 += 64) {
        __syncthreads();
        #pragma unroll
        for (int c = 0; c < 4; c++) {
            int row = c * 32 + srow;
            int ka = (schk ^ (row & 7)) << 3;
            gl_lds16(A + (bm + row) * (size_t)K + k0 + ka,
                     (char*)As + c * 4096 + tid * 16);
            gl_lds16(B + (bn + row) * (size_t)K + k0 + ka,
                     (char*)Bs + c * 4096 + tid * 16);
        }
        __syncthreads();
        #pragma unroll
        for (int kk = 0; kk < 2; kk++) {
            bf16x8 af[4], bfr[4];
            #pragma unroll
            for (int m = 0; m < 4; m++) {
                int row = wm * 64 + m * 16 + r;
                af[m] = *(const bf16x8*)(As + row * 64 + (((kk * 4 + g) ^ (row & 7)) << 3));
            }
            #pragma unroll
            for (int n = 0; n < 4; n++) {
                int row = wn * 64 + n * 16 + r;
                bfr[n] = *(const bf16x8*)(Bs + row * 64 + (((kk * 4 + g) ^ (row & 7)) << 3));
            }
            #pragma unroll
            for (int m = 0; m < 4; m++)
                #pragma unroll
                for (int n = 0; n < 4; n++)
                    acc[m][n] = MFMA(af[m], bfr[n], acc[m][n]);
        }
    }
    #pragma unroll
    for (int m = 0; m < 4; m++)
        #pragma unroll
        for (int n = 0; n < 4; n++)
            #pragma unroll
            for (int j = 0; j < 4; j++) {
                size_t row = bm + wm * 64 + m * 16 + g * 4 + j;
                size_t col = bn + wn * 64 + n * 16 + r;
                bf16 val = (bf16)acc[m][n][j];
                if (col < 3072) qkv3[row * 3072 + col] = val;
                else            vb[row * 1024 + (col - 3072)] = val;
            }
}

// ---------------- per-head RMSNorm + RoPE (q,k) from bf16 qkv3 ----------------
// grid (T, 12), 256 threads: each 128-thread half handles one head-slot.
// slot<16 -> q head, 16..23 -> k head.
__global__ __launch_bounds__(256) void k_normrope(const bf16* __restrict__ qkv3,
                                                  const float* __restrict__ qw,
                                                  const float* __restrict__ kw,
                                                  const int* __restrict__ pos,
                                                  bf16* __restrict__ q,
                                                  bf16* __restrict__ k) {
    const int t = blockIdx.x, tid = threadIdx.x;
    const int half = tid >> 7, d = tid & 127;
    const int slot = blockIdx.y * 2 + half;
    const bool isq = slot < 16;
    const int h = isq ? slot : slot - 16;
    float x = (float)qkv3[(size_t)t * 3072 + slot * 128 + d];
    float ss = x * x;
    #pragma unroll
    for (int m = 32; m; m >>= 1) ss += __shfl_xor(ss, m);
    __shared__ float red[4];
    __shared__ float sh[256];
    if ((tid & 63) == 0) red[tid >> 6] = ss;
    __syncthreads();
    float rs = rsqrtf((red[half * 2] + red[half * 2 + 1]) * (1.0f / HD) + 1e-6f);
    float nx = x * rs * (isq ? qw[d] : kw[d]);
    sh[tid] = nx;
    __syncthreads();
    float other = sh[tid ^ 64];
    int j = d & 63;
    float ang = (float)pos[t] * __powf(10000.f, -(float)j * (1.f / 64.f));
    float s, c;
    __sincosf(ang, &s, &c);
    float o = (d < 64) ? (nx * c - other * s) : (nx * c + other * s);
    bf16* dst = isq ? (q + ((size_t)t * NH + h) * HD + d)
                    : (k + ((size_t)t * NKV + h) * HD + d);
    *dst = (bf16)o;
}

// ---------------- flash attention v6: kv-split + defer-max + nomask fast path --
__global__ __launch_bounds__(256, 3) void k_flash(const bf16* __restrict__ Q,
                                                  const bf16* __restrict__ K,
                                                  const bf16* __restrict__ V,
                                                  bf16* __restrict__ On,
                                                  float* __restrict__ ml) {
    __shared__ __attribute__((aligned(16))) bf16 Ks2[2][64 * 128];  // 32 KB
    __shared__ __attribute__((aligned(16))) bf16 Vt[128 * 64];      // 16 KB

    const int tid = threadIdx.x, lane = tid & 63, w = tid >> 6;
    const int r = lane & 15, g = lane >> 4;
    const int h = blockIdx.x, y = blockIdx.y;
    int ci, qt;
    if (y < 32)      { ci = 0; qt = y; }
    else if (y < 56) { ci = 1; qt = y - 24; }
    else if (y < 72) { ci = 2; qt = y - 40; }
    else             { ci = 3; qt = y - 48; }
    const int c0 = ci * 8;
    const int ntl = min(qt + 1 - c0, 8);
    const int q0 = qt * 64;
    const int gh = h >> 1;
    const int q0w = q0 + w * 16;

    const int rowk = tid >> 4, posc = tid & 15;
    const int vd = tid & 127, vhalf = tid >> 7;

    bf16x8 qf[4];
    #pragma unroll
    for (int ks = 0; ks < 4; ks++)
        qf[ks] = *(const bf16x8*)(Q + ((size_t)(q0w + r) * NH + h) * HD + ks * 32 + g * 8);

    f32x4 acc[8] = {};
    float m_run = -1e30f, l_run = 0.f;
    const float scale = 0.08838834764831845f;

    // ---- prologue: stage tile c0 ----
    {
        const int kv0 = c0 * 64;
        #pragma unroll
        for (int c = 0; c < 4; c++) {
            int row = c * 16 + rowk;
            int srcc = posc ^ (row & 7);
            gl_lds16(K + ((size_t)(kv0 + row) * NKV + gh) * HD + srcc * 8,
                     (char*)&Ks2[0][0] + c * 4096 + tid * 16);
        }
        bf16x8 vr[4];
        #pragma unroll
        for (int it = 0; it < 4; it++) {
            int kb = vhalf + it * 2;
            const bf16* src = V + ((size_t)(kv0 + kb * 8) * NKV + gh) * HD + vd;
            #pragma unroll
            for (int i = 0; i < 8; i++) vr[it][i] = src[(size_t)i * (NKV * HD)];
        }
        #pragma unroll
        for (int it = 0; it < 4; it++) {
            int kb = vhalf + it * 2;
            *(bf16x8*)(&Vt[0] + vd * 64 + ((kb ^ (vd & 7)) * 8)) = vr[it];
        }
        __syncthreads();
    }

    for (int t = 0; t < ntl; ++t) {
        const int b = t & 1;
        const int kv0 = (c0 + t) * 64;
        const bool pf = (t + 1 < ntl);
        bf16x8 vr[4];
        if (pf) {
            const int kv1 = kv0 + 64;
            #pragma unroll
            for (int c = 0; c < 4; c++) {
                int row = c * 16 + rowk;
                int srcc = posc ^ (row & 7);
                gl_lds16(K + ((size_t)(kv1 + row) * NKV + gh) * HD + srcc * 8,
                         (char*)&Ks2[0][0] + (b ^ 1) * 16384 + c * 4096 + tid * 16);
            }
            #pragma unroll
            for (int it = 0; it < 4; it++) {
                int kb = vhalf + it * 2;
                const bf16* src = V + ((size_t)(kv1 + kb * 8) * NKV + gh) * HD + vd;
                #pragma unroll
                for (int i = 0; i < 8; i++) vr[it][i] = src[(size_t)i * (NKV * HD)];
            }
        }
        if (kv0 <= q0w + 15) {
            const bf16* Kb = &Ks2[b][0];
            const char* Vb = (const char*)&Vt[0];
            const bool fullt = (kv0 + 63 <= q0w);  // wave-uniform: no masking needed
            float sc[4][4];
            __builtin_amdgcn_s_setprio(1);
            #pragma unroll
            for (int t4 = 0; t4 < 4; t4++) {
                f32x4 S = {};
                #pragma unroll
                for (int ks = 0; ks < 4; ks++) {
                    int row = t4 * 16 + r;
                    bf16x8 kf = *(const bf16x8*)(Kb + row * 128 + (((4 * ks + g) ^ (row & 7)) * 8));
                    S = MFMA(kf, qf[ks], S);
                }
                if (fullt) {
                    #pragma unroll
                    for (int j = 0; j < 4; j++) sc[t4][j] = S[j] * scale;
                } else {
                    #pragma unroll
                    for (int j = 0; j < 4; j++) {
                        int kg = kv0 + t4 * 16 + 4 * g + j;
                        sc[t4][j] = (kg <= q0w + r) ? S[j] * scale : -1e30f;
                    }
                }
            }
            __builtin_amdgcn_s_setprio(0);
            float mx = sc[0][0];
            #pragma unroll
            for (int t4 = 0; t4 < 4; t4++)
                #pragma unroll
                for (int j = 0; j < 4; j++) mx = fmaxf(mx, sc[t4][j]);
            mx = fmaxf(mx, __shfl_xor(mx, 16));
            mx = fmaxf(mx, __shfl_xor(mx, 32));
            // defer-max (T13): skip rescale when max growth bounded
            const bool nr = __all(mx <= m_run + 8.0f) != 0;
            float mn, alpha;
            if (nr) { mn = m_run; alpha = 1.0f; }
            else    { mn = fmaxf(m_run, mx); alpha = __expf(m_run - mn); m_run = mn; }
            float rsum = 0.f;
            #pragma unroll
            for (int t4 = 0; t4 < 4; t4++)
                #pragma unroll
                for (int j = 0; j < 4; j++) {
                    sc[t4][j] = __expf(sc[t4][j] - mn);
                    rsum += sc[t4][j];
                }
            rsum += __shfl_xor(rsum, 16);
            rsum += __shfl_xor(rsum, 32);
            l_run = l_run * alpha + rsum;
            if (!nr) {
                #pragma unroll
                for (int f = 0; f < 8; f++)
                    #pragma unroll
                    for (int j = 0; j < 4; j++) acc[f][j] *= alpha;
            }
            union PB { uint32_t u[2]; short4v s; };
            PB pbu[4];
            #pragma unroll
            for (int t4 = 0; t4 < 4; t4++) {
                pbu[t4].u[0] = pk2(sc[t4][0], sc[t4][1]);
                pbu[t4].u[1] = pk2(sc[t4][2], sc[t4][3]);
            }
            __builtin_amdgcn_s_setprio(1);
            #pragma unroll
            for (int f = 0; f < 8; f++) {
                #pragma unroll
                for (int t4 = 0; t4 < 4; t4++) {
                    short4v vf = *(const short4v*)(Vb + f * 2048 + r * 128 +
                                  (((2 * t4 + (g >> 1)) ^ (r & 7)) * 16) + (g & 1) * 8);
                    acc[f] = MFMA16(vf, pbu[t4].s, acc[f]);
                }
            }
            __builtin_amdgcn_s_setprio(0);
        }
        if (pf) {
            __syncthreads();
            #pragma unroll
            for (int it = 0; it < 4; it++) {
                int kb = vhalf + it * 2;
                *(bf16x8*)(&Vt[0] + vd * 64 + ((kb ^ (vd & 7)) * 8)) = vr[it];
            }
            __syncthreads();
        }
    }
    const int lr = w * 16 + r;
    float inv_l = 1.0f / l_run;
    bf16* Ob = On + ((size_t)(h * 80 + y)) * 8192 + lr * 128;
    #pragma unroll
    for (int f = 0; f < 8; f++) {
        bf16x4v ov;
        #pragma unroll
        for (int j = 0; j < 4; j++) ov[j] = (bf16)(acc[f][j] * inv_l);
        *(bf16x4v*)(Ob + f * 16 + 4 * g) = ov;
    }
    if (g == 0) {
        float* mlp = ml + ((size_t)(h * 80 + y)) * 128;
        mlp[lr] = m_run;
        mlp[64 + lr] = l_run;
    }
}

// ---------------- combine partials ----------------
__global__ __launch_bounds__(256) void k_comb(const bf16* __restrict__ On,
                                              const float* __restrict__ ml,
                                              bf16* __restrict__ ao) {
    const int h = blockIdx.x, qt = blockIdx.y;
    const int lr = threadIdx.x & 63, db = threadIdx.x >> 6;
    const int nc = 1 + (qt >= 8) + (qt >= 16) + (qt >= 24);
    const int ys[4] = {qt, qt + 24, qt + 40, qt + 48};
    float mi[4], li[4], wi[4];
    float mstar = -1e30f;
    for (int i = 0; i < 4; i++) {
        if (i < nc) {
            const float* p = ml + ((size_t)(h * 80 + ys[i])) * 128;
            mi[i] = p[lr]; li[i] = p[64 + lr];
            mstar = fmaxf(mstar, mi[i]);
        }
    }
    float wsum = 0.f;
    for (int i = 0; i < 4; i++) {
        if (i < nc) { wi[i] = li[i] * __expf(mi[i] - mstar); wsum += wi[i]; }
        else wi[i] = 0.f;
    }
    float inv = 1.f / wsum;
    for (int i = 0; i < 4; i++) wi[i] *= inv;
    const int q = qt * 64 + lr;
    #pragma unroll
    for (int dd = 0; dd < 4; dd++) {
        int d0 = db * 32 + dd * 8;
        float o[8] = {};
        for (int i = 0; i < 4; i++) {
            if (i < nc) {
                bf16x8 v = *(const bf16x8*)(On + ((size_t)(h * 80 + ys[i])) * 8192 + lr * 128 + d0);
                #pragma unroll
                for (int j = 0; j < 8; j++) o[j] += wi[i] * (float)v[j];
            }
        }
        bf16x8 ov;
        #pragma unroll
        for (int j = 0; j < 8; j++) ov[j] = (bf16)o[j];
        *(bf16x8*)(ao + ((size_t)q * NH + h) * HD + d0) = ov;
    }
}

// ---------------- launch ----------------
extern "C" void kernel_launch(void* const* d_in, const int* in_sizes, int n_in,
                              void* d_out, int out_size, void* d_ws, size_t ws_size,
                              hipStream_t stream) {
    const int*   pos  = (const int*)d_in[0];
    const float* hid  = (const float*)d_in[1];
    const float* lw   = (const float*)d_in[2];
    const float* qkvw = (const float*)d_in[3];
    const float* qnw  = (const float*)d_in[4];
    const float* knw  = (const float*)d_in[5];
    const float* ow   = (const float*)d_in[6];
    float* out = (float*)d_out;

    char* ws = (char*)d_ws;
    bf16*  qkvw_b = (bf16*)(ws);                   // 0..16 MB
    bf16*  ow_b   = (bf16*)(ws + (16u << 20));     // 16..24 MB
    bf16*  normed = (bf16*)(ws + (24u << 20));     // 24..32 MB (reused as ao)
    bf16*  qkv3   = (bf16*)(ws + (32u << 20));     // 32..44.6 MB (dead after normrope)
    bf16*  qb     = (bf16*)(ws + (64u << 20));     // 64..72 MB
    bf16*  kb     = (bf16*)(ws + (72u << 20));     // 72..76 MB
    bf16*  vb     = (bf16*)(ws + (76u << 20));     // 76..80 MB
    bf16*  ao     = normed;
    bf16*  On     = (bf16*)(ws + (32u << 20));     // reuses qkv3 region (21 MB)
    float* ml     = (float*)(ws + (54u << 20));    // 54..54.7 MB

    k_f2b<<<4096, 256, 0, stream>>>(qkvw, qkvw_b, 4096 * 2048);
    k_f2b<<<2048, 256, 0, stream>>>(ow, ow_b, 2048 * 2048);
    k_rmsnorm<<<T_N, 256, 0, stream>>>(hid, lw, normed);
    k_gemm_qkv<<<dim3(32, 16), 256, 0, stream>>>(normed, qkvw_b, qkv3, vb);
    k_normrope<<<dim3(T_N, 12), 256, 0, stream>>>(qkv3, qnw, knw, pos, qb, kb);
    k_flash<<<dim3(NH, 80), 256, 0, stream>>>(qb, kb, vb, On, ml);
    k_comb<<<dim3(NH, 32), 256, 0, stream>>>(On, ml, ao);
    k_gemm_bt<<<dim3(16, 16), 256, 0, stream>>>(ao, ow_b, out, 2048, 2048, 2048);
}

// Round 7
// 182.389 us; speedup vs baseline: 1.5227x; 1.0146x over previous
//
#include <hip/hip_runtime.h>
#include <cstdint>
#include <cstddef>

typedef __bf16 bf16;
typedef __attribute__((ext_vector_type(8))) __bf16 bf16x8;
typedef __attribute__((ext_vector_type(4))) __bf16 bf16x4v;
typedef __attribute__((ext_vector_type(4))) float f32x4;
typedef __attribute__((ext_vector_type(4))) short short4v;

#define T_N   2048
#define HID_N 2048
#define NH    16
#define NKV   8
#define HD    128

#define MFMA(a, b, c) __builtin_amdgcn_mfma_f32_16x16x32_bf16((a), (b), (c), 0, 0, 0)

__device__ __forceinline__ f32x4 MFMA16(short4v a, short4v b, f32x4 c) {
#if __has_builtin(__builtin_amdgcn_mfma_f32_16x16x16bf16_1k)
    return __builtin_amdgcn_mfma_f32_16x16x16bf16_1k(a, b, c, 0, 0, 0);
#else
    asm volatile("v_mfma_f32_16x16x16_bf16 %0, %1, %2, %0\n\ts_nop 7\n\ts_nop 7"
                 : "+v"(c) : "v"(a), "v"(b));
    return c;
#endif
}

__device__ __forceinline__ void gl_lds16(const void* g, void* l) {
    __builtin_amdgcn_global_load_lds(
        (const __attribute__((address_space(1))) unsigned int*)g,
        (__attribute__((address_space(3))) unsigned int*)l,
        16, 0, 0);
}

__device__ __forceinline__ uint32_t pk2(float a, float b) {
    union { bf16 h; unsigned short u; } ca, cb;
    ca.h = (bf16)a; cb.h = (bf16)b;
    return ((uint32_t)cb.u << 16) | ca.u;
}

// ---------------- fp32 -> bf16 convert (weights) ----------------
__global__ __launch_bounds__(256) void k_f2b(const float* __restrict__ in,
                                             bf16* __restrict__ out, int n) {
    int i = (blockIdx.x * 256 + threadIdx.x) * 8;
    if (i >= n) return;
    const float4* p = (const float4*)(in + i);
    float4 a = p[0], b = p[1];
    bf16x8 v;
    v[0] = (bf16)a.x; v[1] = (bf16)a.y; v[2] = (bf16)a.z; v[3] = (bf16)a.w;
    v[4] = (bf16)b.x; v[5] = (bf16)b.y; v[6] = (bf16)b.z; v[7] = (bf16)b.w;
    *(bf16x8*)(out + i) = v;
}

// ---------------- hidden RMSNorm -> bf16 ----------------
__global__ __launch_bounds__(256) void k_rmsnorm(const float* __restrict__ x,
                                                 const float* __restrict__ w,
                                                 bf16* __restrict__ out) {
    int row = blockIdx.x, tid = threadIdx.x;
    const float* xr = x + (size_t)row * HID_N;
    float4 a = ((const float4*)xr)[tid * 2];
    float4 b = ((const float4*)xr)[tid * 2 + 1];
    float ss = a.x*a.x + a.y*a.y + a.z*a.z + a.w*a.w
             + b.x*b.x + b.y*b.y + b.z*b.z + b.w*b.w;
    #pragma unroll
    for (int m = 32; m; m >>= 1) ss += __shfl_xor(ss, m);
    __shared__ float red[4];
    if ((tid & 63) == 0) red[tid >> 6] = ss;
    __syncthreads();
    float tot = red[0] + red[1] + red[2] + red[3];
    float rs = rsqrtf(tot * (1.0f / HID_N) + 1e-6f);
    const float4* wr = (const float4*)(w + tid * 8);
    float4 wa = wr[0], wb = wr[1];
    bf16x8 v;
    v[0] = (bf16)(a.x * rs * wa.x); v[1] = (bf16)(a.y * rs * wa.y);
    v[2] = (bf16)(a.z * rs * wa.z); v[3] = (bf16)(a.w * rs * wa.w);
    v[4] = (bf16)(b.x * rs * wb.x); v[5] = (bf16)(b.y * rs * wb.y);
    v[6] = (bf16)(b.z * rs * wb.z); v[7] = (bf16)(b.w * rs * wb.w);
    *(bf16x8*)(out + (size_t)row * HID_N + tid * 8) = v;
}

// ---------------- GEMM: C[M][N] = A[M][K] * B[N][K]^T (bf16 in, fp32 out) ----
__global__ __launch_bounds__(256, 3) void k_gemm_bt(const bf16* __restrict__ A,
                                                    const bf16* __restrict__ B,
                                                    float* __restrict__ C,
                                                    int M, int N, int K) {
    __shared__ __attribute__((aligned(16))) bf16 As[128 * 64];
    __shared__ __attribute__((aligned(16))) bf16 Bs[128 * 64];
    const int tid = threadIdx.x;
    const int lane = tid & 63, wid = tid >> 6;
    const int wm = wid >> 1, wn = wid & 1;
    const int r = lane & 15, g = lane >> 4;
    const size_t bm = (size_t)blockIdx.y * 128, bn = (size_t)blockIdx.x * 128;

    f32x4 acc[4][4] = {};

    const int srow = tid >> 3;
    const int schk = tid & 7;

    for (int k0 = 0; k0 < K; k0 += 64) {
        __syncthreads();
        #pragma unroll
        for (int c = 0; c < 4; c++) {
            int row = c * 32 + srow;
            int ka = (schk ^ (row & 7)) << 3;
            gl_lds16(A + (bm + row) * (size_t)K + k0 + ka,
                     (char*)As + c * 4096 + tid * 16);
            gl_lds16(B + (bn + row) * (size_t)K + k0 + ka,
                     (char*)Bs + c * 4096 + tid * 16);
        }
        __syncthreads();
        #pragma unroll
        for (int kk = 0; kk < 2; kk++) {
            bf16x8 af[4], bfr[4];
            #pragma unroll
            for (int m = 0; m < 4; m++) {
                int row = wm * 64 + m * 16 + r;
                af[m] = *(const bf16x8*)(As + row * 64 + (((kk * 4 + g) ^ (row & 7)) << 3));
            }
            #pragma unroll
            for (int n = 0; n < 4; n++) {
                int row = wn * 64 + n * 16 + r;
                bfr[n] = *(const bf16x8*)(Bs + row * 64 + (((kk * 4 + g) ^ (row & 7)) << 3));
            }
            #pragma unroll
            for (int m = 0; m < 4; m++)
                #pragma unroll
                for (int n = 0; n < 4; n++)
                    acc[m][n] = MFMA(af[m], bfr[n], acc[m][n]);
        }
    }
    #pragma unroll
    for (int m = 0; m < 4; m++)
        #pragma unroll
        for (int n = 0; n < 4; n++)
            #pragma unroll
            for (int j = 0; j < 4; j++) {
                size_t row = bm + wm * 64 + m * 16 + g * 4 + j;
                size_t col = bn + wn * 64 + n * 16 + r;
                C[row * (size_t)N + col] = acc[m][n][j];
            }
}

// ---------------- QKV GEMM variant: bf16 out, v routed to final layout ----------
__global__ __launch_bounds__(256, 3) void k_gemm_qkv(const bf16* __restrict__ A,
                                                     const bf16* __restrict__ B,
                                                     bf16* __restrict__ qkv3,
                                                     bf16* __restrict__ vb) {
    const int K = HID_N;
    __shared__ __attribute__((aligned(16))) bf16 As[128 * 64];
    __shared__ __attribute__((aligned(16))) bf16 Bs[128 * 64];
    const int tid = threadIdx.x;
    const int lane = tid & 63, wid = tid >> 6;
    const int wm = wid >> 1, wn = wid & 1;
    const int r = lane & 15, g = lane >> 4;
    const size_t bm = (size_t)blockIdx.y * 128, bn = (size_t)blockIdx.x * 128;

    f32x4 acc[4][4] = {};
    const int srow = tid >> 3;
    const int schk = tid & 7;

    for (int k0 = 0; k0 < K; k0 += 64) {
        __syncthreads();
        #pragma unroll
        for (int c = 0; c < 4; c++) {
            int row = c * 32 + srow;
            int ka = (schk ^ (row & 7)) << 3;
            gl_lds16(A + (bm + row) * (size_t)K + k0 + ka,
                     (char*)As + c * 4096 + tid * 16);
            gl_lds16(B + (bn + row) * (size_t)K + k0 + ka,
                     (char*)Bs + c * 4096 + tid * 16);
        }
        __syncthreads();
        #pragma unroll
        for (int kk = 0; kk < 2; kk++) {
            bf16x8 af[4], bfr[4];
            #pragma unroll
            for (int m = 0; m < 4; m++) {
                int row = wm * 64 + m * 16 + r;
                af[m] = *(const bf16x8*)(As + row * 64 + (((kk * 4 + g) ^ (row & 7)) << 3));
            }
            #pragma unroll
            for (int n = 0; n < 4; n++) {
                int row = wn * 64 + n * 16 + r;
                bfr[n] = *(const bf16x8*)(Bs + row * 64 + (((kk * 4 + g) ^ (row & 7)) << 3));
            }
            #pragma unroll
            for (int m = 0; m < 4; m++)
                #pragma unroll
                for (int n = 0; n < 4; n++)
                    acc[m][n] = MFMA(af[m], bfr[n], acc[m][n]);
        }
    }
    #pragma unroll
    for (int m = 0; m < 4; m++)
        #pragma unroll
        for (int n = 0; n < 4; n++)
            #pragma unroll
            for (int j = 0; j < 4; j++) {
                size_t row = bm + wm * 64 + m * 16 + g * 4 + j;
                size_t col = bn + wn * 64 + n * 16 + r;
                bf16 val = (bf16)acc[m][n][j];
                if (col < 3072) qkv3[row * 3072 + col] = val;
                else            vb[row * 1024 + (col - 3072)] = val;
            }
}

// ---------------- V transpose: vb[t][c] -> vT[c][t]  (c = hv*128+d) ----------
__global__ __launch_bounds__(256) void k_vt(const bf16* __restrict__ in,
                                            bf16* __restrict__ outp) {
    __shared__ bf16 tile[64][72];
    const int tb = blockIdx.x;   // t tile (32)
    const int db = blockIdx.y;   // col tile (16)
    const int tid = threadIdx.x;
    const int row = tid >> 2, cc = tid & 3;
    const bf16* src = in + (size_t)(tb * 64 + row) * 1024 + db * 64 + cc * 16;
    bf16x8 a = *(const bf16x8*)(src);
    bf16x8 b = *(const bf16x8*)(src + 8);
    #pragma unroll
    for (int i = 0; i < 8; i++) tile[row][cc * 16 + i] = a[i];
    #pragma unroll
    for (int i = 0; i < 8; i++) tile[row][cc * 16 + 8 + i] = b[i];
    __syncthreads();
    bf16* dst = outp + (size_t)(db * 64 + row) * 2048 + tb * 64 + cc * 16;
    bf16x8 o1, o2;
    #pragma unroll
    for (int i = 0; i < 8; i++) o1[i] = tile[cc * 16 + i][row];
    #pragma unroll
    for (int i = 0; i < 8; i++) o2[i] = tile[cc * 16 + 8 + i][row];
    *(bf16x8*)dst = o1;
    *(bf16x8*)(dst + 8) = o2;
}

// ---------------- per-head RMSNorm + RoPE (q,k) from bf16 qkv3 ----------------
__global__ __launch_bounds__(256) void k_normrope(const bf16* __restrict__ qkv3,
                                                  const float* __restrict__ qw,
                                                  const float* __restrict__ kw,
                                                  const int* __restrict__ pos,
                                                  bf16* __restrict__ q,
                                                  bf16* __restrict__ k) {
    const int t = blockIdx.x, tid = threadIdx.x;
    const int half = tid >> 7, d = tid & 127;
    const int slot = blockIdx.y * 2 + half;
    const bool isq = slot < 16;
    const int h = isq ? slot : slot - 16;
    float x = (float)qkv3[(size_t)t * 3072 + slot * 128 + d];
    float ss = x * x;
    #pragma unroll
    for (int m = 32; m; m >>= 1) ss += __shfl_xor(ss, m);
    __shared__ float red[4];
    __shared__ float sh[256];
    if ((tid & 63) == 0) red[tid >> 6] = ss;
    __syncthreads();
    float rs = rsqrtf((red[half * 2] + red[half * 2 + 1]) * (1.0f / HD) + 1e-6f);
    float nx = x * rs * (isq ? qw[d] : kw[d]);
    sh[tid] = nx;
    __syncthreads();
    float other = sh[tid ^ 64];
    int j = d & 63;
    float ang = (float)pos[t] * __powf(10000.f, -(float)j * (1.f / 64.f));
    float s, c;
    __sincosf(ang, &s, &c);
    float o = (d < 64) ? (nx * c - other * s) : (nx * c + other * s);
    bf16* dst = isq ? (q + ((size_t)t * NH + h) * HD + d)
                    : (k + ((size_t)t * NKV + h) * HD + d);
    *dst = (bf16)o;
}

// ---------------- flash attention v7: V staged via gl_lds16 from vT -----------
// kv-split (chunks of 8 tiles); K double-buffered, V single-buffered.
// Per tile: issue V(t)+K(t+1) async -> QK^T+softmax -> vmcnt(4)+barrier ->
// PV -> vmcnt(0)+barrier. Read-side layouts identical to verified R4-R6.
__global__ __launch_bounds__(256, 3) void k_flash(const bf16* __restrict__ Q,
                                                  const bf16* __restrict__ K,
                                                  const bf16* __restrict__ VT,
                                                  bf16* __restrict__ On,
                                                  float* __restrict__ ml) {
    __shared__ __attribute__((aligned(16))) bf16 Ks2[2][64 * 128];  // 32 KB
    __shared__ __attribute__((aligned(16))) bf16 Vt[128 * 64];      // 16 KB

    const int tid = threadIdx.x, lane = tid & 63, w = tid >> 6;
    const int r = lane & 15, g = lane >> 4;
    const int h = blockIdx.x, y = blockIdx.y;
    int ci, qt;
    if (y < 32)      { ci = 0; qt = y; }
    else if (y < 56) { ci = 1; qt = y - 24; }
    else if (y < 72) { ci = 2; qt = y - 40; }
    else             { ci = 3; qt = y - 48; }
    const int c0 = ci * 8;
    const int ntl = min(qt + 1 - c0, 8);
    const int q0 = qt * 64;
    const int gh = h >> 1;
    const int q0w = q0 + w * 16;

    const int rowk = tid >> 4, posc = tid & 15;  // K staging
    const int vrow = tid >> 3, vkb = tid & 7;    // V staging: d = it*32+vrow
    const bf16* VTh = VT + (size_t)gh * 128 * 2048;

    bf16x8 qf[4];
    #pragma unroll
    for (int ks = 0; ks < 4; ks++)
        qf[ks] = *(const bf16x8*)(Q + ((size_t)(q0w + r) * NH + h) * HD + ks * 32 + g * 8);

    f32x4 acc[8] = {};
    float m_run = -1e30f, l_run = 0.f;
    const float scale = 0.08838834764831845f;

    // ---- prologue: stage K(c0), drain ----
    {
        const int kv0 = c0 * 64;
        #pragma unroll
        for (int c = 0; c < 4; c++) {
            int row = c * 16 + rowk;
            int srcc = posc ^ (row & 7);
            gl_lds16(K + ((size_t)(kv0 + row) * NKV + gh) * HD + srcc * 8,
                     (char*)&Ks2[0][0] + c * 4096 + tid * 16);
        }
        asm volatile("s_waitcnt vmcnt(0)" ::: "memory");
        __builtin_amdgcn_s_barrier();
    }

    for (int t = 0; t < ntl; ++t) {
        const int b = t & 1;
        const int kv0 = (c0 + t) * 64;
        const bool pf = (t + 1 < ntl);
        // ---- issue V(t) into Vt (single buffer; linear dest, pre-swz source) ----
        #pragma unroll
        for (int it = 0; it < 4; it++) {
            int d = it * 32 + vrow;
            int srck = (vkb ^ (vrow & 7)) * 8;
            gl_lds16(VTh + (size_t)d * 2048 + kv0 + srck,
                     (char*)&Vt[0] + it * 4096 + tid * 16);
        }
        // ---- issue K(t+1) into Ks2[b^1] ----
        if (pf) {
            const int kv1 = kv0 + 64;
            #pragma unroll
            for (int c = 0; c < 4; c++) {
                int row = c * 16 + rowk;
                int srcc = posc ^ (row & 7);
                gl_lds16(K + ((size_t)(kv1 + row) * NKV + gh) * HD + srcc * 8,
                         (char*)&Ks2[0][0] + (b ^ 1) * 16384 + c * 4096 + tid * 16);
            }
        }
        const bool compute = (kv0 <= q0w + 15);
        union PB { uint32_t u[2]; short4v s; };
        PB pbu[4];
        // ---- phase 1: QK^T + softmax (K(t) ready since last barrier) ----
        if (compute) {
            const bf16* Kb = &Ks2[b][0];
            const bool fullt = (kv0 + 63 <= q0w);
            float sc[4][4];
            __builtin_amdgcn_s_setprio(1);
            #pragma unroll
            for (int t4 = 0; t4 < 4; t4++) {
                f32x4 S = {};
                #pragma unroll
                for (int ks = 0; ks < 4; ks++) {
                    int row = t4 * 16 + r;
                    bf16x8 kf = *(const bf16x8*)(Kb + row * 128 + (((4 * ks + g) ^ (row & 7)) * 8));
                    S = MFMA(kf, qf[ks], S);
                }
                if (fullt) {
                    #pragma unroll
                    for (int j = 0; j < 4; j++) sc[t4][j] = S[j] * scale;
                } else {
                    #pragma unroll
                    for (int j = 0; j < 4; j++) {
                        int kg = kv0 + t4 * 16 + 4 * g + j;
                        sc[t4][j] = (kg <= q0w + r) ? S[j] * scale : -1e30f;
                    }
                }
            }
            __builtin_amdgcn_s_setprio(0);
            float mx = sc[0][0];
            #pragma unroll
            for (int t4 = 0; t4 < 4; t4++)
                #pragma unroll
                for (int j = 0; j < 4; j++) mx = fmaxf(mx, sc[t4][j]);
            mx = fmaxf(mx, __shfl_xor(mx, 16));
            mx = fmaxf(mx, __shfl_xor(mx, 32));
            const bool nr = __all(mx <= m_run + 8.0f) != 0;
            float mn, alpha;
            if (nr) { mn = m_run; alpha = 1.0f; }
            else    { mn = fmaxf(m_run, mx); alpha = __expf(m_run - mn); m_run = mn; }
            float rsum = 0.f;
            #pragma unroll
            for (int t4 = 0; t4 < 4; t4++)
                #pragma unroll
                for (int j = 0; j < 4; j++) {
                    sc[t4][j] = __expf(sc[t4][j] - mn);
                    rsum += sc[t4][j];
                }
            rsum += __shfl_xor(rsum, 16);
            rsum += __shfl_xor(rsum, 32);
            l_run = l_run * alpha + rsum;
            if (!nr) {
                #pragma unroll
                for (int f = 0; f < 8; f++)
                    #pragma unroll
                    for (int j = 0; j < 4; j++) acc[f][j] *= alpha;
            }
            #pragma unroll
            for (int t4 = 0; t4 < 4; t4++) {
                pbu[t4].u[0] = pk2(sc[t4][0], sc[t4][1]);
                pbu[t4].u[1] = pk2(sc[t4][2], sc[t4][3]);
            }
        }
        // ---- V(t) ready across all waves (K(t+1) stays in flight) ----
        if (pf) asm volatile("s_waitcnt vmcnt(4)" ::: "memory");
        else    asm volatile("s_waitcnt vmcnt(0)" ::: "memory");
        __builtin_amdgcn_s_barrier();
        // ---- phase 2: PV ----
        if (compute) {
            const char* Vb = (const char*)&Vt[0];
            __builtin_amdgcn_s_setprio(1);
            #pragma unroll
            for (int f = 0; f < 8; f++) {
                #pragma unroll
                for (int t4 = 0; t4 < 4; t4++) {
                    short4v vf = *(const short4v*)(Vb + f * 2048 + r * 128 +
                                  (((2 * t4 + (g >> 1)) ^ (r & 7)) * 16) + (g & 1) * 8);
                    acc[f] = MFMA16(vf, pbu[t4].s, acc[f]);
                }
            }
            __builtin_amdgcn_s_setprio(0);
        }
        // ---- end of tile: K(t+1) landed; all PV reads of Vt done ----
        asm volatile("s_waitcnt vmcnt(0)" ::: "memory");
        __builtin_amdgcn_s_barrier();
    }
    // ---- epilogue: write normalized partial (bf16) + m,l ----
    const int lr = w * 16 + r;
    float inv_l = 1.0f / l_run;
    bf16* Ob = On + ((size_t)(h * 80 + y)) * 8192 + lr * 128;
    #pragma unroll
    for (int f = 0; f < 8; f++) {
        bf16x4v ov;
        #pragma unroll
        for (int j = 0; j < 4; j++) ov[j] = (bf16)(acc[f][j] * inv_l);
        *(bf16x4v*)(Ob + f * 16 + 4 * g) = ov;
    }
    if (g == 0) {
        float* mlp = ml + ((size_t)(h * 80 + y)) * 128;
        mlp[lr] = m_run;
        mlp[64 + lr] = l_run;
    }
}

// ---------------- combine partials ----------------
__global__ __launch_bounds__(256) void k_comb(const bf16* __restrict__ On,
                                              const float* __restrict__ ml,
                                              bf16* __restrict__ ao) {
    const int h = blockIdx.x, qt = blockIdx.y;
    const int lr = threadIdx.x & 63, db = threadIdx.x >> 6;
    const int nc = 1 + (qt >= 8) + (qt >= 16) + (qt >= 24);
    const int ys[4] = {qt, qt + 24, qt + 40, qt + 48};
    float mi[4], li[4], wi[4];
    float mstar = -1e30f;
    for (int i = 0; i < 4; i++) {
        if (i < nc) {
            const float* p = ml + ((size_t)(h * 80 + ys[i])) * 128;
            mi[i] = p[lr]; li[i] = p[64 + lr];
            mstar = fmaxf(mstar, mi[i]);
        }
    }
    float wsum = 0.f;
    for (int i = 0; i < 4; i++) {
        if (i < nc) { wi[i] = li[i] * __expf(mi[i] - mstar); wsum += wi[i]; }
        else wi[i] = 0.f;
    }
    float inv = 1.f / wsum;
    for (int i = 0; i < 4; i++) wi[i] *= inv;
    const int q = qt * 64 + lr;
    #pragma unroll
    for (int dd = 0; dd < 4; dd++) {
        int d0 = db * 32 + dd * 8;
        float o[8] = {};
        for (int i = 0; i < 4; i++) {
            if (i < nc) {
                bf16x8 v = *(const bf16x8*)(On + ((size_t)(h * 80 + ys[i])) * 8192 + lr * 128 + d0);
                #pragma unroll
                for (int j = 0; j < 8; j++) o[j] += wi[i] * (float)v[j];
            }
        }
        bf16x8 ov;
        #pragma unroll
        for (int j = 0; j < 8; j++) ov[j] = (bf16)o[j];
        *(bf16x8*)(ao + ((size_t)q * NH + h) * HD + d0) = ov;
    }
}

// ---------------- launch ----------------
extern "C" void kernel_launch(void* const* d_in, const int* in_sizes, int n_in,
                              void* d_out, int out_size, void* d_ws, size_t ws_size,
                              hipStream_t stream) {
    const int*   pos  = (const int*)d_in[0];
    const float* hid  = (const float*)d_in[1];
    const float* lw   = (const float*)d_in[2];
    const float* qkvw = (const float*)d_in[3];
    const float* qnw  = (const float*)d_in[4];
    const float* knw  = (const float*)d_in[5];
    const float* ow   = (const float*)d_in[6];
    float* out = (float*)d_out;

    char* ws = (char*)d_ws;
    bf16*  qkvw_b = (bf16*)(ws);                   // 0..16 MB
    bf16*  ow_b   = (bf16*)(ws + (16u << 20));     // 16..24 MB
    bf16*  normed = (bf16*)(ws + (24u << 20));     // 24..32 MB (reused as ao)
    bf16*  qkv3   = (bf16*)(ws + (32u << 20));     // 32..44.6 MB (dead after normrope)
    bf16*  qb     = (bf16*)(ws + (64u << 20));     // 64..72 MB
    bf16*  kb     = (bf16*)(ws + (72u << 20));     // 72..76 MB
    bf16*  vb     = (bf16*)(ws + (76u << 20));     // 76..80 MB
    bf16*  ao     = normed;
    bf16*  On     = (bf16*)(ws + (32u << 20));     // reuses qkv3 region (21 MB)
    float* ml     = (float*)(ws + (54u << 20));    // 54..54.7 MB
    bf16*  vT     = (bf16*)(ws + (56u << 20));     // 56..60 MB (transposed V)

    k_f2b<<<4096, 256, 0, stream>>>(qkvw, qkvw_b, 4096 * 2048);
    k_f2b<<<2048, 256, 0, stream>>>(ow, ow_b, 2048 * 2048);
    k_rmsnorm<<<T_N, 256, 0, stream>>>(hid, lw, normed);
    k_gemm_qkv<<<dim3(32, 16), 256, 0, stream>>>(normed, qkvw_b, qkv3, vb);
    k_vt<<<dim3(32, 16), 256, 0, stream>>>(vb, vT);
    k_normrope<<<dim3(T_N, 12), 256, 0, stream>>>(qkv3, qnw, knw, pos, qb, kb);
    k_flash<<<dim3(NH, 80), 256, 0, stream>>>(qb, kb, vT, On, ml);
    k_comb<<<dim3(NH, 32), 256, 0, stream>>>(On, ml, ao);
    k_gemm_bt<<<dim3(16, 16), 256, 0, stream>>>(ao, ow_b, out, 2048, 2048, 2048);
}

// Round 8
// 181.860 us; speedup vs baseline: 1.5271x; 1.0029x over previous
//
#include <hip/hip_runtime.h>
#include <cstdint>
#include <cstddef>

typedef __bf16 bf16;
typedef __attribute__((ext_vector_type(8))) __bf16 bf16x8;
typedef __attribute__((ext_vector_type(4))) __bf16 bf16x4v;
typedef __attribute__((ext_vector_type(4))) float f32x4;
typedef __attribute__((ext_vector_type(4))) short short4v;

#define T_N   2048
#define HID_N 2048
#define NH    16
#define NKV   8
#define HD    128

#define MFMA(a, b, c) __builtin_amdgcn_mfma_f32_16x16x32_bf16((a), (b), (c), 0, 0, 0)

__device__ __forceinline__ f32x4 MFMA16(short4v a, short4v b, f32x4 c) {
#if __has_builtin(__builtin_amdgcn_mfma_f32_16x16x16bf16_1k)
    return __builtin_amdgcn_mfma_f32_16x16x16bf16_1k(a, b, c, 0, 0, 0);
#else
    asm volatile("v_mfma_f32_16x16x16_bf16 %0, %1, %2, %0\n\ts_nop 7\n\ts_nop 7"
                 : "+v"(c) : "v"(a), "v"(b));
    return c;
#endif
}

__device__ __forceinline__ void gl_lds16(const void* g, void* l) {
    __builtin_amdgcn_global_load_lds(
        (const __attribute__((address_space(1))) unsigned int*)g,
        (__attribute__((address_space(3))) unsigned int*)l,
        16, 0, 0);
}

__device__ __forceinline__ uint32_t pk2(float a, float b) {
    union { bf16 h; unsigned short u; } ca, cb;
    ca.h = (bf16)a; cb.h = (bf16)b;
    return ((uint32_t)cb.u << 16) | ca.u;
}

// heavy-first (ci,qt) <-> y mapping. y 0..51 are the 8-tile blocks; y 52..79
// hold k=7..1 tile blocks (4 per k, one per ci). Inverse used by k_comb.
__device__ __forceinline__ void y2cq(int y, int& ci, int& qt) {
    if (y < 25)       { ci = 0; qt = y + 7; }
    else if (y < 42)  { ci = 1; qt = y - 10; }
    else if (y < 51)  { ci = 2; qt = y - 19; }
    else if (y == 51) { ci = 3; qt = 31; }
    else { int z = y - 52; int k = 7 - (z >> 2); ci = z & 3; qt = 8 * ci + k - 1; }
}
__device__ __forceinline__ int yof(int ci, int qt) {
    int k = qt + 1 - 8 * ci;
    if (k >= 8) {
        if (ci == 0) return qt - 7;
        if (ci == 1) return qt + 10;
        if (ci == 2) return qt + 19;
        return 51;
    }
    return 52 + (7 - k) * 4 + ci;
}

// ---------------- fp32 -> bf16 convert (weights) ----------------
__global__ __launch_bounds__(256) void k_f2b(const float* __restrict__ in,
                                             bf16* __restrict__ out, int n) {
    int i = (blockIdx.x * 256 + threadIdx.x) * 8;
    if (i >= n) return;
    const float4* p = (const float4*)(in + i);
    float4 a = p[0], b = p[1];
    bf16x8 v;
    v[0] = (bf16)a.x; v[1] = (bf16)a.y; v[2] = (bf16)a.z; v[3] = (bf16)a.w;
    v[4] = (bf16)b.x; v[5] = (bf16)b.y; v[6] = (bf16)b.z; v[7] = (bf16)b.w;
    *(bf16x8*)(out + i) = v;
}

// ---------------- hidden RMSNorm -> bf16 ----------------
__global__ __launch_bounds__(256) void k_rmsnorm(const float* __restrict__ x,
                                                 const float* __restrict__ w,
                                                 bf16* __restrict__ out) {
    int row = blockIdx.x, tid = threadIdx.x;
    const float* xr = x + (size_t)row * HID_N;
    float4 a = ((const float4*)xr)[tid * 2];
    float4 b = ((const float4*)xr)[tid * 2 + 1];
    float ss = a.x*a.x + a.y*a.y + a.z*a.z + a.w*a.w
             + b.x*b.x + b.y*b.y + b.z*b.z + b.w*b.w;
    #pragma unroll
    for (int m = 32; m; m >>= 1) ss += __shfl_xor(ss, m);
    __shared__ float red[4];
    if ((tid & 63) == 0) red[tid >> 6] = ss;
    __syncthreads();
    float tot = red[0] + red[1] + red[2] + red[3];
    float rs = rsqrtf(tot * (1.0f / HID_N) + 1e-6f);
    const float4* wr = (const float4*)(w + tid * 8);
    float4 wa = wr[0], wb = wr[1];
    bf16x8 v;
    v[0] = (bf16)(a.x * rs * wa.x); v[1] = (bf16)(a.y * rs * wa.y);
    v[2] = (bf16)(a.z * rs * wa.z); v[3] = (bf16)(a.w * rs * wa.w);
    v[4] = (bf16)(b.x * rs * wb.x); v[5] = (bf16)(b.y * rs * wb.y);
    v[6] = (bf16)(b.z * rs * wb.z); v[7] = (bf16)(b.w * rs * wb.w);
    *(bf16x8*)(out + (size_t)row * HID_N + tid * 8) = v;
}

// ---------------- GEMM: C[M][N] = A[M][K] * B[N][K]^T (bf16 in, fp32 out) ----
__global__ __launch_bounds__(256, 3) void k_gemm_bt(const bf16* __restrict__ A,
                                                    const bf16* __restrict__ B,
                                                    float* __restrict__ C,
                                                    int M, int N, int K) {
    __shared__ __attribute__((aligned(16))) bf16 As[128 * 64];
    __shared__ __attribute__((aligned(16))) bf16 Bs[128 * 64];
    const int tid = threadIdx.x;
    const int lane = tid & 63, wid = tid >> 6;
    const int wm = wid >> 1, wn = wid & 1;
    const int r = lane & 15, g = lane >> 4;
    const size_t bm = (size_t)blockIdx.y * 128, bn = (size_t)blockIdx.x * 128;

    f32x4 acc[4][4] = {};

    const int srow = tid >> 3;
    const int schk = tid & 7;

    for (int k0 = 0; k0 < K; k0 += 64) {
        __syncthreads();
        #pragma unroll
        for (int c = 0; c < 4; c++) {
            int row = c * 32 + srow;
            int ka = (schk ^ (row & 7)) << 3;
            gl_lds16(A + (bm + row) * (size_t)K + k0 + ka,
                     (char*)As + c * 4096 + tid * 16);
            gl_lds16(B + (bn + row) * (size_t)K + k0 + ka,
                     (char*)Bs + c * 4096 + tid * 16);
        }
        __syncthreads();
        #pragma unroll
        for (int kk = 0; kk < 2; kk++) {
            bf16x8 af[4], bfr[4];
            #pragma unroll
            for (int m = 0; m < 4; m++) {
                int row = wm * 64 + m * 16 + r;
                af[m] = *(const bf16x8*)(As + row * 64 + (((kk * 4 + g) ^ (row & 7)) << 3));
            }
            #pragma unroll
            for (int n = 0; n < 4; n++) {
                int row = wn * 64 + n * 16 + r;
                bfr[n] = *(const bf16x8*)(Bs + row * 64 + (((kk * 4 + g) ^ (row & 7)) << 3));
            }
            #pragma unroll
            for (int m = 0; m < 4; m++)
                #pragma unroll
                for (int n = 0; n < 4; n++)
                    acc[m][n] = MFMA(af[m], bfr[n], acc[m][n]);
        }
    }
    #pragma unroll
    for (int m = 0; m < 4; m++)
        #pragma unroll
        for (int n = 0; n < 4; n++)
            #pragma unroll
            for (int j = 0; j < 4; j++) {
                size_t row = bm + wm * 64 + m * 16 + g * 4 + j;
                size_t col = bn + wn * 64 + n * 16 + r;
                C[row * (size_t)N + col] = acc[m][n][j];
            }
}

// ---------------- QKV GEMM variant: bf16 out, v routed to final layout ----------
__global__ __launch_bounds__(256, 3) void k_gemm_qkv(const bf16* __restrict__ A,
                                                     const bf16* __restrict__ B,
                                                     bf16* __restrict__ qkv3,
                                                     bf16* __restrict__ vb) {
    const int K = HID_N;
    __shared__ __attribute__((aligned(16))) bf16 As[128 * 64];
    __shared__ __attribute__((aligned(16))) bf16 Bs[128 * 64];
    const int tid = threadIdx.x;
    const int lane = tid & 63, wid = tid >> 6;
    const int wm = wid >> 1, wn = wid & 1;
    const int r = lane & 15, g = lane >> 4;
    const size_t bm = (size_t)blockIdx.y * 128, bn = (size_t)blockIdx.x * 128;

    f32x4 acc[4][4] = {};
    const int srow = tid >> 3;
    const int schk = tid & 7;

    for (int k0 = 0; k0 < K; k0 += 64) {
        __syncthreads();
        #pragma unroll
        for (int c = 0; c < 4; c++) {
            int row = c * 32 + srow;
            int ka = (schk ^ (row & 7)) << 3;
            gl_lds16(A + (bm + row) * (size_t)K + k0 + ka,
                     (char*)As + c * 4096 + tid * 16);
            gl_lds16(B + (bn + row) * (size_t)K + k0 + ka,
                     (char*)Bs + c * 4096 + tid * 16);
        }
        __syncthreads();
        #pragma unroll
        for (int kk = 0; kk < 2; kk++) {
            bf16x8 af[4], bfr[4];
            #pragma unroll
            for (int m = 0; m < 4; m++) {
                int row = wm * 64 + m * 16 + r;
                af[m] = *(const bf16x8*)(As + row * 64 + (((kk * 4 + g) ^ (row & 7)) << 3));
            }
            #pragma unroll
            for (int n = 0; n < 4; n++) {
                int row = wn * 64 + n * 16 + r;
                bfr[n] = *(const bf16x8*)(Bs + row * 64 + (((kk * 4 + g) ^ (row & 7)) << 3));
            }
            #pragma unroll
            for (int m = 0; m < 4; m++)
                #pragma unroll
                for (int n = 0; n < 4; n++)
                    acc[m][n] = MFMA(af[m], bfr[n], acc[m][n]);
        }
    }
    #pragma unroll
    for (int m = 0; m < 4; m++)
        #pragma unroll
        for (int n = 0; n < 4; n++)
            #pragma unroll
            for (int j = 0; j < 4; j++) {
                size_t row = bm + wm * 64 + m * 16 + g * 4 + j;
                size_t col = bn + wn * 64 + n * 16 + r;
                bf16 val = (bf16)acc[m][n][j];
                if (col < 3072) qkv3[row * 3072 + col] = val;
                else            vb[row * 1024 + (col - 3072)] = val;
            }
}

// ---------------- V transpose: vb[t][c] -> vT[c][t]  (c = hv*128+d) ----------
__global__ __launch_bounds__(256) void k_vt(const bf16* __restrict__ in,
                                            bf16* __restrict__ outp) {
    __shared__ bf16 tile[64][72];
    const int tb = blockIdx.x;   // t tile (32)
    const int db = blockIdx.y;   // col tile (16)
    const int tid = threadIdx.x;
    const int row = tid >> 2, cc = tid & 3;
    const bf16* src = in + (size_t)(tb * 64 + row) * 1024 + db * 64 + cc * 16;
    bf16x8 a = *(const bf16x8*)(src);
    bf16x8 b = *(const bf16x8*)(src + 8);
    #pragma unroll
    for (int i = 0; i < 8; i++) tile[row][cc * 16 + i] = a[i];
    #pragma unroll
    for (int i = 0; i < 8; i++) tile[row][cc * 16 + 8 + i] = b[i];
    __syncthreads();
    bf16* dst = outp + (size_t)(db * 64 + row) * 2048 + tb * 64 + cc * 16;
    bf16x8 o1, o2;
    #pragma unroll
    for (int i = 0; i < 8; i++) o1[i] = tile[cc * 16 + i][row];
    #pragma unroll
    for (int i = 0; i < 8; i++) o2[i] = tile[cc * 16 + 8 + i][row];
    *(bf16x8*)dst = o1;
    *(bf16x8*)(dst + 8) = o2;
}

// ---------------- per-head RMSNorm + RoPE (q,k) from bf16 qkv3 ----------------
__global__ __launch_bounds__(256) void k_normrope(const bf16* __restrict__ qkv3,
                                                  const float* __restrict__ qw,
                                                  const float* __restrict__ kw,
                                                  const int* __restrict__ pos,
                                                  bf16* __restrict__ q,
                                                  bf16* __restrict__ k) {
    const int t = blockIdx.x, tid = threadIdx.x;
    const int half = tid >> 7, d = tid & 127;
    const int slot = blockIdx.y * 2 + half;
    const bool isq = slot < 16;
    const int h = isq ? slot : slot - 16;
    float x = (float)qkv3[(size_t)t * 3072 + slot * 128 + d];
    float ss = x * x;
    #pragma unroll
    for (int m = 32; m; m >>= 1) ss += __shfl_xor(ss, m);
    __shared__ float red[4];
    __shared__ float sh[256];
    if ((tid & 63) == 0) red[tid >> 6] = ss;
    __syncthreads();
    float rs = rsqrtf((red[half * 2] + red[half * 2 + 1]) * (1.0f / HD) + 1e-6f);
    float nx = x * rs * (isq ? qw[d] : kw[d]);
    sh[tid] = nx;
    __syncthreads();
    float other = sh[tid ^ 64];
    int j = d & 63;
    float ang = (float)pos[t] * __powf(10000.f, -(float)j * (1.f / 64.f));
    float s, c;
    __sincosf(ang, &s, &c);
    float o = (d < 64) ? (nx * c - other * s) : (nx * c + other * s);
    bf16* dst = isq ? (q + ((size_t)t * NH + h) * HD + d)
                    : (k + ((size_t)t * NKV + h) * HD + d);
    *dst = (bf16)o;
}

// ---------------- flash attention v8: heavy-first dispatch ordering -----------
__global__ __launch_bounds__(256, 3) void k_flash(const bf16* __restrict__ Q,
                                                  const bf16* __restrict__ K,
                                                  const bf16* __restrict__ VT,
                                                  bf16* __restrict__ On,
                                                  float* __restrict__ ml) {
    __shared__ __attribute__((aligned(16))) bf16 Ks2[2][64 * 128];  // 32 KB
    __shared__ __attribute__((aligned(16))) bf16 Vt[128 * 64];      // 16 KB

    const int tid = threadIdx.x, lane = tid & 63, w = tid >> 6;
    const int r = lane & 15, g = lane >> 4;
    const int h = blockIdx.x, y = blockIdx.y;
    int ci, qt;
    y2cq(y, ci, qt);
    const int c0 = ci * 8;
    const int ntl = min(qt + 1 - c0, 8);
    const int q0 = qt * 64;
    const int gh = h >> 1;
    const int q0w = q0 + w * 16;

    const int rowk = tid >> 4, posc = tid & 15;  // K staging
    const int vrow = tid >> 3, vkb = tid & 7;    // V staging
    const bf16* VTh = VT + (size_t)gh * 128 * 2048;

    bf16x8 qf[4];
    #pragma unroll
    for (int ks = 0; ks < 4; ks++)
        qf[ks] = *(const bf16x8*)(Q + ((size_t)(q0w + r) * NH + h) * HD + ks * 32 + g * 8);

    f32x4 acc[8] = {};
    float m_run = -1e30f, l_run = 0.f;
    const float scale = 0.08838834764831845f;

    // ---- prologue: stage K(c0), drain ----
    {
        const int kv0 = c0 * 64;
        #pragma unroll
        for (int c = 0; c < 4; c++) {
            int row = c * 16 + rowk;
            int srcc = posc ^ (row & 7);
            gl_lds16(K + ((size_t)(kv0 + row) * NKV + gh) * HD + srcc * 8,
                     (char*)&Ks2[0][0] + c * 4096 + tid * 16);
        }
        asm volatile("s_waitcnt vmcnt(0)" ::: "memory");
        __builtin_amdgcn_s_barrier();
    }

    for (int t = 0; t < ntl; ++t) {
        const int b = t & 1;
        const int kv0 = (c0 + t) * 64;
        const bool pf = (t + 1 < ntl);
        // ---- issue V(t) into Vt (single buffer; linear dest, pre-swz source) ----
        #pragma unroll
        for (int it = 0; it < 4; it++) {
            int d = it * 32 + vrow;
            int srck = (vkb ^ (vrow & 7)) * 8;
            gl_lds16(VTh + (size_t)d * 2048 + kv0 + srck,
                     (char*)&Vt[0] + it * 4096 + tid * 16);
        }
        // ---- issue K(t+1) into Ks2[b^1] ----
        if (pf) {
            const int kv1 = kv0 + 64;
            #pragma unroll
            for (int c = 0; c < 4; c++) {
                int row = c * 16 + rowk;
                int srcc = posc ^ (row & 7);
                gl_lds16(K + ((size_t)(kv1 + row) * NKV + gh) * HD + srcc * 8,
                         (char*)&Ks2[0][0] + (b ^ 1) * 16384 + c * 4096 + tid * 16);
            }
        }
        const bool compute = (kv0 <= q0w + 15);
        union PB { uint32_t u[2]; short4v s; };
        PB pbu[4];
        // ---- phase 1: QK^T + softmax ----
        if (compute) {
            const bf16* Kb = &Ks2[b][0];
            const bool fullt = (kv0 + 63 <= q0w);
            float sc[4][4];
            __builtin_amdgcn_s_setprio(1);
            #pragma unroll
            for (int t4 = 0; t4 < 4; t4++) {
                f32x4 S = {};
                #pragma unroll
                for (int ks = 0; ks < 4; ks++) {
                    int row = t4 * 16 + r;
                    bf16x8 kf = *(const bf16x8*)(Kb + row * 128 + (((4 * ks + g) ^ (row & 7)) * 8));
                    S = MFMA(kf, qf[ks], S);
                }
                if (fullt) {
                    #pragma unroll
                    for (int j = 0; j < 4; j++) sc[t4][j] = S[j] * scale;
                } else {
                    #pragma unroll
                    for (int j = 0; j < 4; j++) {
                        int kg = kv0 + t4 * 16 + 4 * g + j;
                        sc[t4][j] = (kg <= q0w + r) ? S[j] * scale : -1e30f;
                    }
                }
            }
            __builtin_amdgcn_s_setprio(0);
            float mx = sc[0][0];
            #pragma unroll
            for (int t4 = 0; t4 < 4; t4++)
                #pragma unroll
                for (int j = 0; j < 4; j++) mx = fmaxf(mx, sc[t4][j]);
            mx = fmaxf(mx, __shfl_xor(mx, 16));
            mx = fmaxf(mx, __shfl_xor(mx, 32));
            const bool nr = __all(mx <= m_run + 8.0f) != 0;
            float mn, alpha;
            if (nr) { mn = m_run; alpha = 1.0f; }
            else    { mn = fmaxf(m_run, mx); alpha = __expf(m_run - mn); m_run = mn; }
            float rsum = 0.f;
            #pragma unroll
            for (int t4 = 0; t4 < 4; t4++)
                #pragma unroll
                for (int j = 0; j < 4; j++) {
                    sc[t4][j] = __expf(sc[t4][j] - mn);
                    rsum += sc[t4][j];
                }
            rsum += __shfl_xor(rsum, 16);
            rsum += __shfl_xor(rsum, 32);
            l_run = l_run * alpha + rsum;
            if (!nr) {
                #pragma unroll
                for (int f = 0; f < 8; f++)
                    #pragma unroll
                    for (int j = 0; j < 4; j++) acc[f][j] *= alpha;
            }
            #pragma unroll
            for (int t4 = 0; t4 < 4; t4++) {
                pbu[t4].u[0] = pk2(sc[t4][0], sc[t4][1]);
                pbu[t4].u[1] = pk2(sc[t4][2], sc[t4][3]);
            }
        }
        // ---- V(t) ready across all waves (K(t+1) stays in flight) ----
        if (pf) asm volatile("s_waitcnt vmcnt(4)" ::: "memory");
        else    asm volatile("s_waitcnt vmcnt(0)" ::: "memory");
        __builtin_amdgcn_s_barrier();
        // ---- phase 2: PV ----
        if (compute) {
            const char* Vb = (const char*)&Vt[0];
            __builtin_amdgcn_s_setprio(1);
            #pragma unroll
            for (int f = 0; f < 8; f++) {
                #pragma unroll
                for (int t4 = 0; t4 < 4; t4++) {
                    short4v vf = *(const short4v*)(Vb + f * 2048 + r * 128 +
                                  (((2 * t4 + (g >> 1)) ^ (r & 7)) * 16) + (g & 1) * 8);
                    acc[f] = MFMA16(vf, pbu[t4].s, acc[f]);
                }
            }
            __builtin_amdgcn_s_setprio(0);
        }
        // ---- end of tile: K(t+1) landed; all PV reads of Vt done ----
        asm volatile("s_waitcnt vmcnt(0)" ::: "memory");
        __builtin_amdgcn_s_barrier();
    }
    // ---- epilogue: write normalized partial (bf16) + m,l ----
    const int lr = w * 16 + r;
    float inv_l = 1.0f / l_run;
    bf16* Ob = On + ((size_t)(h * 80 + y)) * 8192 + lr * 128;
    #pragma unroll
    for (int f = 0; f < 8; f++) {
        bf16x4v ov;
        #pragma unroll
        for (int j = 0; j < 4; j++) ov[j] = (bf16)(acc[f][j] * inv_l);
        *(bf16x4v*)(Ob + f * 16 + 4 * g) = ov;
    }
    if (g == 0) {
        float* mlp = ml + ((size_t)(h * 80 + y)) * 128;
        mlp[lr] = m_run;
        mlp[64 + lr] = l_run;
    }
}

// ---------------- combine partials (coalesced reads/writes) ----------------
__global__ __launch_bounds__(256) void k_comb(const bf16* __restrict__ On,
                                              const float* __restrict__ ml,
                                              bf16* __restrict__ ao) {
    const int h = blockIdx.x, qt = blockIdx.y;
    const int tid = threadIdx.x;
    const int dc = tid & 15;      // 16B chunk of d
    const int qr = tid >> 4;      // q row within pass (16 rows/pass)
    const int nc = 1 + (qt >= 8) + (qt >= 16) + (qt >= 24);
    int ys[4];
    #pragma unroll
    for (int i = 0; i < 4; i++) ys[i] = (i < nc) ? yof(i, qt) : 0;
    #pragma unroll
    for (int p = 0; p < 4; p++) {
        const int lq = p * 16 + qr;
        float mi[4], li[4], wi[4];
        float mstar = -1e30f;
        for (int i = 0; i < 4; i++) {
            if (i < nc) {
                const float* pml = ml + ((size_t)(h * 80 + ys[i])) * 128;
                mi[i] = pml[lq]; li[i] = pml[64 + lq];
                mstar = fmaxf(mstar, mi[i]);
            }
        }
        float wsum = 0.f;
        for (int i = 0; i < 4; i++) {
            if (i < nc) { wi[i] = li[i] * __expf(mi[i] - mstar); wsum += wi[i]; }
            else wi[i] = 0.f;
        }
        float inv = 1.f / wsum;
        float o[8] = {};
        for (int i = 0; i < 4; i++) {
            if (i < nc) {
                bf16x8 v = *(const bf16x8*)(On + ((size_t)(h * 80 + ys[i])) * 8192 +
                                            lq * 128 + dc * 8);
                float wn = wi[i] * inv;
                #pragma unroll
                for (int j = 0; j < 8; j++) o[j] += wn * (float)v[j];
            }
        }
        bf16x8 ov;
        #pragma unroll
        for (int j = 0; j < 8; j++) ov[j] = (bf16)o[j];
        const int q = qt * 64 + lq;
        *(bf16x8*)(ao + ((size_t)q * NH + h) * HD + dc * 8) = ov;
    }
}

// ---------------- launch ----------------
extern "C" void kernel_launch(void* const* d_in, const int* in_sizes, int n_in,
                              void* d_out, int out_size, void* d_ws, size_t ws_size,
                              hipStream_t stream) {
    const int*   pos  = (const int*)d_in[0];
    const float* hid  = (const float*)d_in[1];
    const float* lw   = (const float*)d_in[2];
    const float* qkvw = (const float*)d_in[3];
    const float* qnw  = (const float*)d_in[4];
    const float* knw  = (const float*)d_in[5];
    const float* ow   = (const float*)d_in[6];
    float* out = (float*)d_out;

    char* ws = (char*)d_ws;
    bf16*  qkvw_b = (bf16*)(ws);                   // 0..16 MB
    bf16*  ow_b   = (bf16*)(ws + (16u << 20));     // 16..24 MB
    bf16*  normed = (bf16*)(ws + (24u << 20));     // 24..32 MB (reused as ao)
    bf16*  qkv3   = (bf16*)(ws + (32u << 20));     // 32..44.6 MB (dead after normrope)
    bf16*  qb     = (bf16*)(ws + (64u << 20));     // 64..72 MB
    bf16*  kb     = (bf16*)(ws + (72u << 20));     // 72..76 MB
    bf16*  vb     = (bf16*)(ws + (76u << 20));     // 76..80 MB
    bf16*  ao     = normed;
    bf16*  On     = (bf16*)(ws + (32u << 20));     // reuses qkv3 region (21 MB)
    float* ml     = (float*)(ws + (54u << 20));    // 54..54.7 MB
    bf16*  vT     = (bf16*)(ws + (56u << 20));     // 56..60 MB (transposed V)

    k_f2b<<<4096, 256, 0, stream>>>(qkvw, qkvw_b, 4096 * 2048);
    k_f2b<<<2048, 256, 0, stream>>>(ow, ow_b, 2048 * 2048);
    k_rmsnorm<<<T_N, 256, 0, stream>>>(hid, lw, normed);
    k_gemm_qkv<<<dim3(32, 16), 256, 0, stream>>>(normed, qkvw_b, qkv3, vb);
    k_vt<<<dim3(32, 16), 256, 0, stream>>>(vb, vT);
    k_normrope<<<dim3(T_N, 12), 256, 0, stream>>>(qkv3, qnw, knw, pos, qb, kb);
    k_flash<<<dim3(NH, 80), 256, 0, stream>>>(qb, kb, vT, On, ml);
    k_comb<<<dim3(NH, 32), 256, 0, stream>>>(On, ml, ao);
    k_gemm_bt<<<dim3(16, 16), 256, 0, stream>>>(ao, ow_b, out, 2048, 2048, 2048);
}

// Round 9
// 175.639 us; speedup vs baseline: 1.5812x; 1.0354x over previous
//
#include <hip/hip_runtime.h>
#include <cstdint>
#include <cstddef>

typedef __bf16 bf16;
typedef __attribute__((ext_vector_type(8))) __bf16 bf16x8;
typedef __attribute__((ext_vector_type(4))) __bf16 bf16x4v;
typedef __attribute__((ext_vector_type(4))) float f32x4;
typedef __attribute__((ext_vector_type(4))) short short4v;

#define T_N   2048
#define HID_N 2048
#define NH    16
#define NKV   8
#define HD    128

#define MFMA(a, b, c) __builtin_amdgcn_mfma_f32_16x16x32_bf16((a), (b), (c), 0, 0, 0)

__device__ __forceinline__ f32x4 MFMA16(short4v a, short4v b, f32x4 c) {
#if __has_builtin(__builtin_amdgcn_mfma_f32_16x16x16bf16_1k)
    return __builtin_amdgcn_mfma_f32_16x16x16bf16_1k(a, b, c, 0, 0, 0);
#else
    asm volatile("v_mfma_f32_16x16x16_bf16 %0, %1, %2, %0\n\ts_nop 7\n\ts_nop 7"
                 : "+v"(c) : "v"(a), "v"(b));
    return c;
#endif
}

__device__ __forceinline__ void gl_lds16(const void* g, void* l) {
    __builtin_amdgcn_global_load_lds(
        (const __attribute__((address_space(1))) unsigned int*)g,
        (__attribute__((address_space(3))) unsigned int*)l,
        16, 0, 0);
}

__device__ __forceinline__ uint32_t pk2(float a, float b) {
    union { bf16 h; unsigned short u; } ca, cb;
    ca.h = (bf16)a; cb.h = (bf16)b;
    return ((uint32_t)cb.u << 16) | ca.u;
}

// heavy-first (ci,qt) <-> y mapping (flash kv-split). Inverse used by k_comb.
__device__ __forceinline__ void y2cq(int y, int& ci, int& qt) {
    if (y < 25)       { ci = 0; qt = y + 7; }
    else if (y < 42)  { ci = 1; qt = y - 10; }
    else if (y < 51)  { ci = 2; qt = y - 19; }
    else if (y == 51) { ci = 3; qt = 31; }
    else { int z = y - 52; int k = 7 - (z >> 2); ci = z & 3; qt = 8 * ci + k - 1; }
}
__device__ __forceinline__ int yof(int ci, int qt) {
    int k = qt + 1 - 8 * ci;
    if (k >= 8) {
        if (ci == 0) return qt - 7;
        if (ci == 1) return qt + 10;
        if (ci == 2) return qt + 19;
        return 51;
    }
    return 52 + (7 - k) * 4 + ci;
}

// ---------------- fp32 -> bf16 convert (both weights, one launch) -------------
__global__ __launch_bounds__(256) void k_f2b2(const float* __restrict__ a,
                                              bf16* __restrict__ oa, int na,
                                              const float* __restrict__ b,
                                              bf16* __restrict__ ob, int nb) {
    int i = (blockIdx.x * 256 + threadIdx.x) * 8;
    const float* src; bf16* dst; int j;
    if (i < na) { src = a + i; dst = oa + i; }
    else { j = i - na; if (j >= nb) return; src = b + j; dst = ob + j; }
    float4 x = ((const float4*)src)[0], y = ((const float4*)src)[1];
    bf16x8 v;
    v[0] = (bf16)x.x; v[1] = (bf16)x.y; v[2] = (bf16)x.z; v[3] = (bf16)x.w;
    v[4] = (bf16)y.x; v[5] = (bf16)y.y; v[6] = (bf16)y.z; v[7] = (bf16)y.w;
    *(bf16x8*)dst = v;
}

// ---------------- hidden RMSNorm -> bf16 ----------------
__global__ __launch_bounds__(256) void k_rmsnorm(const float* __restrict__ x,
                                                 const float* __restrict__ w,
                                                 bf16* __restrict__ out) {
    int row = blockIdx.x, tid = threadIdx.x;
    const float* xr = x + (size_t)row * HID_N;
    float4 a = ((const float4*)xr)[tid * 2];
    float4 b = ((const float4*)xr)[tid * 2 + 1];
    float ss = a.x*a.x + a.y*a.y + a.z*a.z + a.w*a.w
             + b.x*b.x + b.y*b.y + b.z*b.z + b.w*b.w;
    #pragma unroll
    for (int m = 32; m; m >>= 1) ss += __shfl_xor(ss, m);
    __shared__ float red[4];
    if ((tid & 63) == 0) red[tid >> 6] = ss;
    __syncthreads();
    float tot = red[0] + red[1] + red[2] + red[3];
    float rs = rsqrtf(tot * (1.0f / HID_N) + 1e-6f);
    const float4* wr = (const float4*)(w + tid * 8);
    float4 wa = wr[0], wb = wr[1];
    bf16x8 v;
    v[0] = (bf16)(a.x * rs * wa.x); v[1] = (bf16)(a.y * rs * wa.y);
    v[2] = (bf16)(a.z * rs * wa.z); v[3] = (bf16)(a.w * rs * wa.w);
    v[4] = (bf16)(b.x * rs * wb.x); v[5] = (bf16)(b.y * rs * wb.y);
    v[6] = (bf16)(b.z * rs * wb.z); v[7] = (bf16)(b.w * rs * wb.w);
    *(bf16x8*)(out + (size_t)row * HID_N + tid * 8) = v;
}

// ---------------- O-proj GEMM: 64x128 tile (2 blocks/CU), XCD swizzle ---------
// C[M][N] = A[M][K] * B[N][K]^T, fp32 out. M=N=K=2048, grid (16,32)=512.
__global__ __launch_bounds__(256, 3) void k_gemm_bt64(const bf16* __restrict__ A,
                                                      const bf16* __restrict__ B,
                                                      float* __restrict__ C,
                                                      int M, int N, int K) {
    __shared__ __attribute__((aligned(16))) bf16 As[64 * 64];    // 8 KB
    __shared__ __attribute__((aligned(16))) bf16 Bs[128 * 64];   // 16 KB
    const int tid = threadIdx.x;
    const int lane = tid & 63, wid = tid >> 6;
    const int r = lane & 15, g = lane >> 4;
    // bijective XCD swizzle: nwg=512, nbx=16
    const int orig = blockIdx.y * gridDim.x + blockIdx.x;
    const int wgid = (orig & 7) * 64 + (orig >> 3);
    const size_t bm = (size_t)(wgid >> 4) * 64, bn = (size_t)(wgid & 15) * 128;

    f32x4 acc[4][2] = {};
    const int srow = tid >> 3;   // 0..31
    const int schk = tid & 7;

    for (int k0 = 0; k0 < K; k0 += 64) {
        __syncthreads();
        #pragma unroll
        for (int c = 0; c < 2; c++) {
            int row = c * 32 + srow;
            int ka = (schk ^ (row & 7)) << 3;
            gl_lds16(A + (bm + row) * (size_t)K + k0 + ka,
                     (char*)As + c * 4096 + tid * 16);
        }
        #pragma unroll
        for (int c = 0; c < 4; c++) {
            int row = c * 32 + srow;
            int ka = (schk ^ (row & 7)) << 3;
            gl_lds16(B + (bn + row) * (size_t)K + k0 + ka,
                     (char*)Bs + c * 4096 + tid * 16);
        }
        __syncthreads();
        #pragma unroll
        for (int kk = 0; kk < 2; kk++) {
            bf16x8 af[4], bfr[2];
            #pragma unroll
            for (int m = 0; m < 4; m++) {
                int row = m * 16 + r;
                af[m] = *(const bf16x8*)(As + row * 64 + (((kk * 4 + g) ^ (row & 7)) << 3));
            }
            #pragma unroll
            for (int n = 0; n < 2; n++) {
                int row = wid * 32 + n * 16 + r;
                bfr[n] = *(const bf16x8*)(Bs + row * 64 + (((kk * 4 + g) ^ (row & 7)) << 3));
            }
            #pragma unroll
            for (int m = 0; m < 4; m++)
                #pragma unroll
                for (int n = 0; n < 2; n++)
                    acc[m][n] = MFMA(af[m], bfr[n], acc[m][n]);
        }
    }
    #pragma unroll
    for (int m = 0; m < 4; m++)
        #pragma unroll
        for (int n = 0; n < 2; n++)
            #pragma unroll
            for (int j = 0; j < 4; j++) {
                size_t row = bm + m * 16 + g * 4 + j;
                size_t col = bn + wid * 32 + n * 16 + r;
                C[row * (size_t)N + col] = acc[m][n][j];
            }
}

// ---------------- QKV GEMM: 128x128, bf16 out, v routed, XCD swizzle ----------
__global__ __launch_bounds__(256, 3) void k_gemm_qkv(const bf16* __restrict__ A,
                                                     const bf16* __restrict__ B,
                                                     bf16* __restrict__ qkv3,
                                                     bf16* __restrict__ vb) {
    const int K = HID_N;
    __shared__ __attribute__((aligned(16))) bf16 As[128 * 64];
    __shared__ __attribute__((aligned(16))) bf16 Bs[128 * 64];
    const int tid = threadIdx.x;
    const int lane = tid & 63, wid = tid >> 6;
    const int wm = wid >> 1, wn = wid & 1;
    const int r = lane & 15, g = lane >> 4;
    // bijective XCD swizzle: nwg=512, nbx=32
    const int orig = blockIdx.y * gridDim.x + blockIdx.x;
    const int wgid = (orig & 7) * 64 + (orig >> 3);
    const size_t bm = (size_t)(wgid >> 5) * 128, bn = (size_t)(wgid & 31) * 128;

    f32x4 acc[4][4] = {};
    const int srow = tid >> 3;
    const int schk = tid & 7;

    for (int k0 = 0; k0 < K; k0 += 64) {
        __syncthreads();
        #pragma unroll
        for (int c = 0; c < 4; c++) {
            int row = c * 32 + srow;
            int ka = (schk ^ (row & 7)) << 3;
            gl_lds16(A + (bm + row) * (size_t)K + k0 + ka,
                     (char*)As + c * 4096 + tid * 16);
            gl_lds16(B + (bn + row) * (size_t)K + k0 + ka,
                     (char*)Bs + c * 4096 + tid * 16);
        }
        __syncthreads();
        #pragma unroll
        for (int kk = 0; kk < 2; kk++) {
            bf16x8 af[4], bfr[4];
            #pragma unroll
            for (int m = 0; m < 4; m++) {
                int row = wm * 64 + m * 16 + r;
                af[m] = *(const bf16x8*)(As + row * 64 + (((kk * 4 + g) ^ (row & 7)) << 3));
            }
            #pragma unroll
            for (int n = 0; n < 4; n++) {
                int row = wn * 64 + n * 16 + r;
                bfr[n] = *(const bf16x8*)(Bs + row * 64 + (((kk * 4 + g) ^ (row & 7)) << 3));
            }
            #pragma unroll
            for (int m = 0; m < 4; m++)
                #pragma unroll
                for (int n = 0; n < 4; n++)
                    acc[m][n] = MFMA(af[m], bfr[n], acc[m][n]);
        }
    }
    #pragma unroll
    for (int m = 0; m < 4; m++)
        #pragma unroll
        for (int n = 0; n < 4; n++)
            #pragma unroll
            for (int j = 0; j < 4; j++) {
                size_t row = bm + wm * 64 + m * 16 + g * 4 + j;
                size_t col = bn + wn * 64 + n * 16 + r;
                bf16 val = (bf16)acc[m][n][j];
                if (col < 3072) qkv3[row * 3072 + col] = val;
                else            vb[row * 1024 + (col - 3072)] = val;
            }
}

// ---------------- V transpose: vb[t][c] -> vT[c][t]  (c = hv*128+d) ----------
__global__ __launch_bounds__(256) void k_vt(const bf16* __restrict__ in,
                                            bf16* __restrict__ outp) {
    __shared__ bf16 tile[64][72];
    const int tb = blockIdx.x;
    const int db = blockIdx.y;
    const int tid = threadIdx.x;
    const int row = tid >> 2, cc = tid & 3;
    const bf16* src = in + (size_t)(tb * 64 + row) * 1024 + db * 64 + cc * 16;
    bf16x8 a = *(const bf16x8*)(src);
    bf16x8 b = *(const bf16x8*)(src + 8);
    #pragma unroll
    for (int i = 0; i < 8; i++) tile[row][cc * 16 + i] = a[i];
    #pragma unroll
    for (int i = 0; i < 8; i++) tile[row][cc * 16 + 8 + i] = b[i];
    __syncthreads();
    bf16* dst = outp + (size_t)(db * 64 + row) * 2048 + tb * 64 + cc * 16;
    bf16x8 o1, o2;
    #pragma unroll
    for (int i = 0; i < 8; i++) o1[i] = tile[cc * 16 + i][row];
    #pragma unroll
    for (int i = 0; i < 8; i++) o2[i] = tile[cc * 16 + 8 + i][row];
    *(bf16x8*)dst = o1;
    *(bf16x8*)(dst + 8) = o2;
}

// ---------------- per-head RMSNorm + RoPE (q,k) from bf16 qkv3 ----------------
__global__ __launch_bounds__(256) void k_normrope(const bf16* __restrict__ qkv3,
                                                  const float* __restrict__ qw,
                                                  const float* __restrict__ kw,
                                                  const int* __restrict__ pos,
                                                  bf16* __restrict__ q,
                                                  bf16* __restrict__ k) {
    const int t = blockIdx.x, tid = threadIdx.x;
    const int half = tid >> 7, d = tid & 127;
    const int slot = blockIdx.y * 2 + half;
    const bool isq = slot < 16;
    const int h = isq ? slot : slot - 16;
    float x = (float)qkv3[(size_t)t * 3072 + slot * 128 + d];
    float ss = x * x;
    #pragma unroll
    for (int m = 32; m; m >>= 1) ss += __shfl_xor(ss, m);
    __shared__ float red[4];
    __shared__ float sh[256];
    if ((tid & 63) == 0) red[tid >> 6] = ss;
    __syncthreads();
    float rs = rsqrtf((red[half * 2] + red[half * 2 + 1]) * (1.0f / HD) + 1e-6f);
    float nx = x * rs * (isq ? qw[d] : kw[d]);
    sh[tid] = nx;
    __syncthreads();
    float other = sh[tid ^ 64];
    int j = d & 63;
    float ang = (float)pos[t] * __powf(10000.f, -(float)j * (1.f / 64.f));
    float s, c;
    __sincosf(ang, &s, &c);
    float o = (d < 64) ? (nx * c - other * s) : (nx * c + other * s);
    bf16* dst = isq ? (q + ((size_t)t * NH + h) * HD + d)
                    : (k + ((size_t)t * NKV + h) * HD + d);
    *dst = (bf16)o;
}

// ---------------- flash attention (R8-verified, unchanged) --------------------
__global__ __launch_bounds__(256, 3) void k_flash(const bf16* __restrict__ Q,
                                                  const bf16* __restrict__ K,
                                                  const bf16* __restrict__ VT,
                                                  bf16* __restrict__ On,
                                                  float* __restrict__ ml) {
    __shared__ __attribute__((aligned(16))) bf16 Ks2[2][64 * 128];  // 32 KB
    __shared__ __attribute__((aligned(16))) bf16 Vt[128 * 64];      // 16 KB

    const int tid = threadIdx.x, lane = tid & 63, w = tid >> 6;
    const int r = lane & 15, g = lane >> 4;
    const int h = blockIdx.x, y = blockIdx.y;
    int ci, qt;
    y2cq(y, ci, qt);
    const int c0 = ci * 8;
    const int ntl = min(qt + 1 - c0, 8);
    const int q0 = qt * 64;
    const int gh = h >> 1;
    const int q0w = q0 + w * 16;

    const int rowk = tid >> 4, posc = tid & 15;
    const int vrow = tid >> 3, vkb = tid & 7;
    const bf16* VTh = VT + (size_t)gh * 128 * 2048;

    bf16x8 qf[4];
    #pragma unroll
    for (int ks = 0; ks < 4; ks++)
        qf[ks] = *(const bf16x8*)(Q + ((size_t)(q0w + r) * NH + h) * HD + ks * 32 + g * 8);

    f32x4 acc[8] = {};
    float m_run = -1e30f, l_run = 0.f;
    const float scale = 0.08838834764831845f;

    {
        const int kv0 = c0 * 64;
        #pragma unroll
        for (int c = 0; c < 4; c++) {
            int row = c * 16 + rowk;
            int srcc = posc ^ (row & 7);
            gl_lds16(K + ((size_t)(kv0 + row) * NKV + gh) * HD + srcc * 8,
                     (char*)&Ks2[0][0] + c * 4096 + tid * 16);
        }
        asm volatile("s_waitcnt vmcnt(0)" ::: "memory");
        __builtin_amdgcn_s_barrier();
    }

    for (int t = 0; t < ntl; ++t) {
        const int b = t & 1;
        const int kv0 = (c0 + t) * 64;
        const bool pf = (t + 1 < ntl);
        #pragma unroll
        for (int it = 0; it < 4; it++) {
            int d = it * 32 + vrow;
            int srck = (vkb ^ (vrow & 7)) * 8;
            gl_lds16(VTh + (size_t)d * 2048 + kv0 + srck,
                     (char*)&Vt[0] + it * 4096 + tid * 16);
        }
        if (pf) {
            const int kv1 = kv0 + 64;
            #pragma unroll
            for (int c = 0; c < 4; c++) {
                int row = c * 16 + rowk;
                int srcc = posc ^ (row & 7);
                gl_lds16(K + ((size_t)(kv1 + row) * NKV + gh) * HD + srcc * 8,
                         (char*)&Ks2[0][0] + (b ^ 1) * 16384 + c * 4096 + tid * 16);
            }
        }
        const bool compute = (kv0 <= q0w + 15);
        union PB { uint32_t u[2]; short4v s; };
        PB pbu[4];
        if (compute) {
            const bf16* Kb = &Ks2[b][0];
            const bool fullt = (kv0 + 63 <= q0w);
            float sc[4][4];
            __builtin_amdgcn_s_setprio(1);
            #pragma unroll
            for (int t4 = 0; t4 < 4; t4++) {
                f32x4 S = {};
                #pragma unroll
                for (int ks = 0; ks < 4; ks++) {
                    int row = t4 * 16 + r;
                    bf16x8 kf = *(const bf16x8*)(Kb + row * 128 + (((4 * ks + g) ^ (row & 7)) * 8));
                    S = MFMA(kf, qf[ks], S);
                }
                if (fullt) {
                    #pragma unroll
                    for (int j = 0; j < 4; j++) sc[t4][j] = S[j] * scale;
                } else {
                    #pragma unroll
                    for (int j = 0; j < 4; j++) {
                        int kg = kv0 + t4 * 16 + 4 * g + j;
                        sc[t4][j] = (kg <= q0w + r) ? S[j] * scale : -1e30f;
                    }
                }
            }
            __builtin_amdgcn_s_setprio(0);
            float mx = sc[0][0];
            #pragma unroll
            for (int t4 = 0; t4 < 4; t4++)
                #pragma unroll
                for (int j = 0; j < 4; j++) mx = fmaxf(mx, sc[t4][j]);
            mx = fmaxf(mx, __shfl_xor(mx, 16));
            mx = fmaxf(mx, __shfl_xor(mx, 32));
            const bool nr = __all(mx <= m_run + 8.0f) != 0;
            float mn, alpha;
            if (nr) { mn = m_run; alpha = 1.0f; }
            else    { mn = fmaxf(m_run, mx); alpha = __expf(m_run - mn); m_run = mn; }
            float rsum = 0.f;
            #pragma unroll
            for (int t4 = 0; t4 < 4; t4++)
                #pragma unroll
                for (int j = 0; j < 4; j++) {
                    sc[t4][j] = __expf(sc[t4][j] - mn);
                    rsum += sc[t4][j];
                }
            rsum += __shfl_xor(rsum, 16);
            rsum += __shfl_xor(rsum, 32);
            l_run = l_run * alpha + rsum;
            if (!nr) {
                #pragma unroll
                for (int f = 0; f < 8; f++)
                    #pragma unroll
                    for (int j = 0; j < 4; j++) acc[f][j] *= alpha;
            }
            #pragma unroll
            for (int t4 = 0; t4 < 4; t4++) {
                pbu[t4].u[0] = pk2(sc[t4][0], sc[t4][1]);
                pbu[t4].u[1] = pk2(sc[t4][2], sc[t4][3]);
            }
        }
        if (pf) asm volatile("s_waitcnt vmcnt(4)" ::: "memory");
        else    asm volatile("s_waitcnt vmcnt(0)" ::: "memory");
        __builtin_amdgcn_s_barrier();
        if (compute) {
            const char* Vb = (const char*)&Vt[0];
            __builtin_amdgcn_s_setprio(1);
            #pragma unroll
            for (int f = 0; f < 8; f++) {
                #pragma unroll
                for (int t4 = 0; t4 < 4; t4++) {
                    short4v vf = *(const short4v*)(Vb + f * 2048 + r * 128 +
                                  (((2 * t4 + (g >> 1)) ^ (r & 7)) * 16) + (g & 1) * 8);
                    acc[f] = MFMA16(vf, pbu[t4].s, acc[f]);
                }
            }
            __builtin_amdgcn_s_setprio(0);
        }
        asm volatile("s_waitcnt vmcnt(0)" ::: "memory");
        __builtin_amdgcn_s_barrier();
    }
    const int lr = w * 16 + r;
    float inv_l = 1.0f / l_run;
    bf16* Ob = On + ((size_t)(h * 80 + y)) * 8192 + lr * 128;
    #pragma unroll
    for (int f = 0; f < 8; f++) {
        bf16x4v ov;
        #pragma unroll
        for (int j = 0; j < 4; j++) ov[j] = (bf16)(acc[f][j] * inv_l);
        *(bf16x4v*)(Ob + f * 16 + 4 * g) = ov;
    }
    if (g == 0) {
        float* mlp = ml + ((size_t)(h * 80 + y)) * 128;
        mlp[lr] = m_run;
        mlp[64 + lr] = l_run;
    }
}

// ---------------- combine partials (coalesced) ----------------
__global__ __launch_bounds__(256) void k_comb(const bf16* __restrict__ On,
                                              const float* __restrict__ ml,
                                              bf16* __restrict__ ao) {
    const int h = blockIdx.x, qt = blockIdx.y;
    const int tid = threadIdx.x;
    const int dc = tid & 15;
    const int qr = tid >> 4;
    const int nc = 1 + (qt >= 8) + (qt >= 16) + (qt >= 24);
    int ys[4];
    #pragma unroll
    for (int i = 0; i < 4; i++) ys[i] = (i < nc) ? yof(i, qt) : 0;
    #pragma unroll
    for (int p = 0; p < 4; p++) {
        const int lq = p * 16 + qr;
        float mi[4], li[4], wi[4];
        float mstar = -1e30f;
        for (int i = 0; i < 4; i++) {
            if (i < nc) {
                const float* pml = ml + ((size_t)(h * 80 + ys[i])) * 128;
                mi[i] = pml[lq]; li[i] = pml[64 + lq];
                mstar = fmaxf(mstar, mi[i]);
            }
        }
        float wsum = 0.f;
        for (int i = 0; i < 4; i++) {
            if (i < nc) { wi[i] = li[i] * __expf(mi[i] - mstar); wsum += wi[i]; }
            else wi[i] = 0.f;
        }
        float inv = 1.f / wsum;
        float o[8] = {};
        for (int i = 0; i < 4; i++) {
            if (i < nc) {
                bf16x8 v = *(const bf16x8*)(On + ((size_t)(h * 80 + ys[i])) * 8192 +
                                            lq * 128 + dc * 8);
                float wn = wi[i] * inv;
                #pragma unroll
                for (int j = 0; j < 8; j++) o[j] += wn * (float)v[j];
            }
        }
        bf16x8 ov;
        #pragma unroll
        for (int j = 0; j < 8; j++) ov[j] = (bf16)o[j];
        const int q = qt * 64 + lq;
        *(bf16x8*)(ao + ((size_t)q * NH + h) * HD + dc * 8) = ov;
    }
}

// ---------------- launch ----------------
extern "C" void kernel_launch(void* const* d_in, const int* in_sizes, int n_in,
                              void* d_out, int out_size, void* d_ws, size_t ws_size,
                              hipStream_t stream) {
    const int*   pos  = (const int*)d_in[0];
    const float* hid  = (const float*)d_in[1];
    const float* lw   = (const float*)d_in[2];
    const float* qkvw = (const float*)d_in[3];
    const float* qnw  = (const float*)d_in[4];
    const float* knw  = (const float*)d_in[5];
    const float* ow   = (const float*)d_in[6];
    float* out = (float*)d_out;

    char* ws = (char*)d_ws;
    bf16*  qkvw_b = (bf16*)(ws);                   // 0..16 MB
    bf16*  ow_b   = (bf16*)(ws + (16u << 20));     // 16..24 MB
    bf16*  normed = (bf16*)(ws + (24u << 20));     // 24..32 MB (reused as ao)
    bf16*  qkv3   = (bf16*)(ws + (32u << 20));     // 32..44.6 MB (dead after normrope)
    bf16*  qb     = (bf16*)(ws + (64u << 20));     // 64..72 MB
    bf16*  kb     = (bf16*)(ws + (72u << 20));     // 72..76 MB
    bf16*  vb     = (bf16*)(ws + (76u << 20));     // 76..80 MB
    bf16*  ao     = normed;
    bf16*  On     = (bf16*)(ws + (32u << 20));     // reuses qkv3 region (21 MB)
    float* ml     = (float*)(ws + (54u << 20));    // 54..54.7 MB
    bf16*  vT     = (bf16*)(ws + (56u << 20));     // 56..60 MB (transposed V)

    k_f2b2<<<6144, 256, 0, stream>>>(qkvw, qkvw_b, 4096 * 2048, ow, ow_b, 2048 * 2048);
    k_rmsnorm<<<T_N, 256, 0, stream>>>(hid, lw, normed);
    k_gemm_qkv<<<dim3(32, 16), 256, 0, stream>>>(normed, qkvw_b, qkv3, vb);
    k_vt<<<dim3(32, 16), 256, 0, stream>>>(vb, vT);
    k_normrope<<<dim3(T_N, 12), 256, 0, stream>>>(qkv3, qnw, knw, pos, qb, kb);
    k_flash<<<dim3(NH, 80), 256, 0, stream>>>(qb, kb, vT, On, ml);
    k_comb<<<dim3(NH, 32), 256, 0, stream>>>(On, ml, ao);
    k_gemm_bt64<<<dim3(16, 32), 256, 0, stream>>>(ao, ow_b, out, 2048, 2048, 2048);
}